// Round 3
// baseline (395.883 us; speedup 1.0000x reference)
//
#include <hip/hip_runtime.h>
#include <hip/hip_bf16.h>

// CVRPModel: B=16, P=200, N=2000, D=128.
// Inputs f32, OUTPUT f32 (ref is f32 softmax; out_npz 23.7MB = 6.4M f32).
// ws layout (floats): sq[B*P*D] | ekk[B*N*256] ([ekv 0..127 | ek 128..255]) | aft[B*P*D]

#define BB 16
#define PP 200
#define NN 2000
#define DD 128

// ---------------- K1: q = q1*Wq1^T + q2*Wq2^T + cat(last,load,left)*Wql^T; sq = sigmoid(q)
// grid: (B*P)/8 x 128 threads; thread d owns output dim d for 8 rows.
__global__ __launch_bounds__(128) void k_qproj(
    const float* __restrict__ q1, const float* __restrict__ q2,
    const float* __restrict__ last, const float* __restrict__ loadv,
    const float* __restrict__ leftv, const float* __restrict__ Wq1,
    const float* __restrict__ Wq2, const float* __restrict__ Wql,
    float* __restrict__ sq_out)
{
  __shared__ float s1[8][DD], s2[8][DD], s3[8][DD];
  const int d = threadIdx.x;
  const int bp0 = blockIdx.x * 8;
  {
    const float4* g1 = (const float4*)(q1 + (size_t)bp0 * DD);
    const float4* g2 = (const float4*)(q2 + (size_t)bp0 * DD);
    const float4* g3 = (const float4*)(last + (size_t)bp0 * DD);
    float4* t1 = (float4*)&s1[0][0];
    float4* t2 = (float4*)&s2[0][0];
    float4* t3 = (float4*)&s3[0][0];
    #pragma unroll
    for (int k = 0; k < 2; k++){
      const int ii = d + k * 128;            // 256 float4 = 8 rows x 128 f32
      t1[ii] = g1[ii]; t2[ii] = g2[ii]; t3[ii] = g3[ii];
    }
  }
  __syncthreads();
  float acc[8] = {0,0,0,0,0,0,0,0};
  const float4* w1 = (const float4*)(Wq1 + (size_t)d * DD);
  const float4* w2 = (const float4*)(Wq2 + (size_t)d * DD);
  #pragma unroll 8
  for (int i = 0; i < 32; i++){
    const float4 f = w1[i];
    const int e = i * 4;
    #pragma unroll
    for (int r = 0; r < 8; r++)
      acc[r] += s1[r][e]*f.x + s1[r][e+1]*f.y + s1[r][e+2]*f.z + s1[r][e+3]*f.w;
  }
  #pragma unroll 8
  for (int i = 0; i < 32; i++){
    const float4 f = w2[i];
    const int e = i * 4;
    #pragma unroll
    for (int r = 0; r < 8; r++)
      acc[r] += s2[r][e]*f.x + s2[r][e+1]*f.y + s2[r][e+2]*f.z + s2[r][e+3]*f.w;
  }
  // Wq_last row d: D+2=130 f32, row stride 520B -> scalar loads.
  const float* wl = Wql + (size_t)d * (DD + 2);
  for (int e = 0; e < DD; e++){
    const float w = wl[e];
    #pragma unroll
    for (int r = 0; r < 8; r++) acc[r] += s3[r][e] * w;
  }
  const float wld = wl[DD], wlf = wl[DD+1];
  #pragma unroll
  for (int r = 0; r < 8; r++){
    const int bp = bp0 + r;
    const float qv = acc[r] + loadv[bp] * wld + leftv[bp] * wlf;
    sq_out[(size_t)bp * DD + d] = 1.f / (1.f + expf(-qv));
  }
}

// ---------------- K2: k=nodes*Wk^T, v=nodes*Wv^T; ekk = [exp(k)*v | exp(k)]
// grid: (B*N)/8 x 128 threads.
__global__ __launch_bounds__(128) void k_kv(
    const float* __restrict__ nodes, const float* __restrict__ Wk,
    const float* __restrict__ Wv, float* __restrict__ ekk)
{
  __shared__ float ns[8][DD];
  const int d = threadIdx.x;
  const size_t n0 = (size_t)blockIdx.x * 8;   // global row in [0, B*N)
  {
    const float4* g = (const float4*)(nodes + n0 * DD);
    float4* t = (float4*)&ns[0][0];
    #pragma unroll
    for (int k = 0; k < 2; k++){ const int ii = d + k * 128; t[ii] = g[ii]; }
  }
  __syncthreads();
  float ak[8] = {0,0,0,0,0,0,0,0};
  float av[8] = {0,0,0,0,0,0,0,0};
  const float4* wk = (const float4*)(Wk + (size_t)d * DD);
  const float4* wv = (const float4*)(Wv + (size_t)d * DD);
  #pragma unroll 8
  for (int i = 0; i < 32; i++){
    const float4 f = wk[i];
    const float4 g = wv[i];
    const int e = i * 4;
    #pragma unroll
    for (int r = 0; r < 8; r++){
      const float n0v = ns[r][e], n1 = ns[r][e+1], n2 = ns[r][e+2], n3 = ns[r][e+3];
      ak[r] += n0v*f.x + n1*f.y + n2*f.z + n3*f.w;
      av[r] += n0v*g.x + n1*g.y + n2*g.z + n3*g.w;
    }
  }
  #pragma unroll
  for (int r = 0; r < 8; r++){
    const float ek = expf(ak[r]);
    float* o = ekk + (n0 + r) * 256;
    o[d]      = ek * av[r];
    o[DD + d] = ek;
  }
}

// ---------------- K3: e_alpha = exp(-ls*aa*dist + mask); bias/denom = e_alpha x ekk;
// aft = sigmoid_q * bias/(denom+1e-20). grid: (P/8, B) x 256; thread owns ekk col tid.
__global__ __launch_bounds__(256) void k_aft(
    const float* __restrict__ dist, const float* __restrict__ ninf,
    const float* __restrict__ ekk, const float* __restrict__ sq,
    const float* __restrict__ log_scale, const float* __restrict__ aft_alpha,
    float* __restrict__ aft)
{
  __shared__ float ea[8][128];
  __shared__ float accs[8][256];
  const int tid = threadIdx.x;
  const int b = blockIdx.y;
  const int p0 = blockIdx.x * 8;
  const float scale = log_scale[0] * aft_alpha[0];
  float acc[8] = {0,0,0,0,0,0,0,0};
  for (int n0 = 0; n0 < NN; n0 += 128){
    const int nch = min(128, NN - n0);
    #pragma unroll
    for (int k = 0; k < 4; k++){
      const int ii = tid + k * 256;          // 1024 = 8 rows x 128 cols
      const int p = ii >> 7, nn = ii & 127;
      if (nn < nch){
        const size_t off = (size_t)(b * PP + p0 + p) * NN + n0 + nn;
        ea[p][nn] = expf(ninf[off] - scale * dist[off]);
      }
    }
    __syncthreads();
    const float* ecol = ekk + (size_t)(b * NN + n0) * 256 + tid;
    #pragma unroll 4
    for (int nn = 0; nn < nch; nn++){
      const float val = ecol[(size_t)nn * 256];
      #pragma unroll
      for (int p = 0; p < 8; p++) acc[p] += ea[p][nn] * val;
    }
    __syncthreads();
  }
  #pragma unroll
  for (int p = 0; p < 8; p++) accs[p][tid] = acc[p];
  __syncthreads();
  if (tid < DD){
    #pragma unroll
    for (int p = 0; p < 8; p++){
      const float bias = accs[p][tid];
      const float den  = accs[p][tid + DD];
      const size_t o = (size_t)(b * PP + p0 + p) * DD + tid;
      aft[o] = sq[o] * (bias / (den + 1e-20f));
    }
  }
}

// ---------------- K4: score = aft.nodes/sqrt(D) - ls*pa*dist; 10*tanh + mask; softmax over N.
// grid: (P/4, B) x 256 threads. Output f32.
__global__ __launch_bounds__(256) void k_score(
    const float* __restrict__ aft, const float* __restrict__ nodes,
    const float* __restrict__ dist, const float* __restrict__ ninf,
    const float* __restrict__ log_scale, const float* __restrict__ probs_alpha,
    float* __restrict__ out)
{
  __shared__ float afts[4][DD];
  __shared__ float score_s[4][NN];
  __shared__ float red[4][256];
  const int tid = threadIdx.x;
  const int b = blockIdx.y;
  const int p0 = blockIdx.x * 4;
  const float spb = log_scale[0] * probs_alpha[0];
  for (int ii = tid; ii < 4 * DD; ii += 256)
    afts[ii >> 7][ii & 127] = aft[(size_t)(b * PP + p0) * DD + ii];
  __syncthreads();
  float pmax[4] = {-1e30f,-1e30f,-1e30f,-1e30f};
  const float isd = 0.088388347648318447f;  // 1/sqrt(128)
  for (int n = tid; n < NN; n += 256){
    const float4* nr = (const float4*)(nodes + (size_t)(b * NN + n) * DD);
    float dot[4] = {0,0,0,0};
    #pragma unroll 8
    for (int i = 0; i < 32; i++){
      const float4 f = nr[i];
      #pragma unroll
      for (int p = 0; p < 4; p++){
        const float4 a = ((const float4*)&afts[p][0])[i];
        dot[p] += a.x*f.x + a.y*f.y + a.z*f.z + a.w*f.w;
      }
    }
    #pragma unroll
    for (int p = 0; p < 4; p++){
      const size_t off = (size_t)(b * PP + p0 + p) * NN + n;
      const float sc = dot[p] * isd - spb * dist[off];
      const float s = 10.f * tanhf(sc) + ninf[off];
      score_s[p][n] = s;
      pmax[p] = fmaxf(pmax[p], s);
    }
  }
  #pragma unroll
  for (int p = 0; p < 4; p++) red[p][tid] = pmax[p];
  __syncthreads();
  for (int s = 128; s > 0; s >>= 1){
    if (tid < s){
      #pragma unroll
      for (int p = 0; p < 4; p++) red[p][tid] = fmaxf(red[p][tid], red[p][tid+s]);
    }
    __syncthreads();
  }
  float mx[4];
  #pragma unroll
  for (int p = 0; p < 4; p++) mx[p] = red[p][0];
  __syncthreads();
  float psum[4] = {0,0,0,0};
  for (int n = tid; n < NN; n += 256){
    #pragma unroll
    for (int p = 0; p < 4; p++){
      const float e = expf(score_s[p][n] - mx[p]);
      score_s[p][n] = e;
      psum[p] += e;
    }
  }
  #pragma unroll
  for (int p = 0; p < 4; p++) red[p][tid] = psum[p];
  __syncthreads();
  for (int s = 128; s > 0; s >>= 1){
    if (tid < s){
      #pragma unroll
      for (int p = 0; p < 4; p++) red[p][tid] += red[p][tid+s];
    }
    __syncthreads();
  }
  float inv[4];
  #pragma unroll
  for (int p = 0; p < 4; p++) inv[p] = 1.f / red[p][0];
  for (int n = tid; n < NN; n += 256){
    #pragma unroll
    for (int p = 0; p < 4; p++)
      out[(size_t)(b * PP + p0 + p) * NN + n] = score_s[p][n] * inv[p];
  }
}

extern "C" void kernel_launch(void* const* d_in, const int* in_sizes, int n_in,
                              void* d_out, int out_size, void* d_ws, size_t ws_size,
                              hipStream_t stream)
{
  const float* nodes = (const float*)d_in[0];
  const float* last  = (const float*)d_in[1];
  const float* q1    = (const float*)d_in[2];
  const float* q2    = (const float*)d_in[3];
  const float* loadv = (const float*)d_in[4];
  const float* leftv = (const float*)d_in[5];
  const float* dist  = (const float*)d_in[6];
  const float* ninf  = (const float*)d_in[7];
  const float* ls    = (const float*)d_in[8];
  const float* Wq1   = (const float*)d_in[9];
  const float* Wq2   = (const float*)d_in[10];
  const float* Wql   = (const float*)d_in[11];
  const float* Wk    = (const float*)d_in[12];
  const float* Wv    = (const float*)d_in[13];
  const float* aa    = (const float*)d_in[14];
  const float* pa    = (const float*)d_in[15];
  float* out = (float*)d_out;

  float* sq  = (float*)d_ws;
  float* ekk = sq + (size_t)BB * PP * DD;
  float* aft = ekk + (size_t)BB * NN * 256;

  k_qproj<<<dim3((BB * PP) / 8), dim3(128), 0, stream>>>(q1, q2, last, loadv, leftv, Wq1, Wq2, Wql, sq);
  k_kv<<<dim3((BB * NN) / 8), dim3(128), 0, stream>>>(nodes, Wk, Wv, ekk);
  k_aft<<<dim3(PP / 8, BB), dim3(256), 0, stream>>>(dist, ninf, ekk, sq, ls, aa, aft);
  k_score<<<dim3(PP / 4, BB), dim3(256), 0, stream>>>(aft, nodes, dist, ninf, ls, pa, out);
}

// Round 4
// 231.069 us; speedup vs baseline: 1.7133x; 1.7133x over previous
//
#include <hip/hip_runtime.h>
#include <hip/hip_bf16.h>

// CVRPModel: B=16, P=200, N=2000, D=128. Inputs f32, output f32.
// ws (floats): sq[409600] | ekk[8192000] | aft[409600] | partial[4*16*224*256]
//   score[16*200*2000] overlaps partial (partials dead after k_aft_reduce).
// total ~94.8 MB.

#define BB 16
#define PP 200
#define NN 2000
#define DD 128
#define KSPLIT 4
#define KSLICE 500          // NN / KSPLIT
#define MT 32               // p-tile in k_aft_gemm
#define MPAD 224            // 7 * 32

// ---------------- K1: q projections + sigmoid (unchanged from passing version)
__global__ __launch_bounds__(128) void k_qproj(
    const float* __restrict__ q1, const float* __restrict__ q2,
    const float* __restrict__ last, const float* __restrict__ loadv,
    const float* __restrict__ leftv, const float* __restrict__ Wq1,
    const float* __restrict__ Wq2, const float* __restrict__ Wql,
    float* __restrict__ sq_out)
{
  __shared__ float s1[8][DD], s2[8][DD], s3[8][DD];
  const int d = threadIdx.x;
  const int bp0 = blockIdx.x * 8;
  {
    const float4* g1 = (const float4*)(q1 + (size_t)bp0 * DD);
    const float4* g2 = (const float4*)(q2 + (size_t)bp0 * DD);
    const float4* g3 = (const float4*)(last + (size_t)bp0 * DD);
    float4* t1 = (float4*)&s1[0][0];
    float4* t2 = (float4*)&s2[0][0];
    float4* t3 = (float4*)&s3[0][0];
    #pragma unroll
    for (int k = 0; k < 2; k++){
      const int ii = d + k * 128;
      t1[ii] = g1[ii]; t2[ii] = g2[ii]; t3[ii] = g3[ii];
    }
  }
  __syncthreads();
  float acc[8] = {0,0,0,0,0,0,0,0};
  const float4* w1 = (const float4*)(Wq1 + (size_t)d * DD);
  const float4* w2 = (const float4*)(Wq2 + (size_t)d * DD);
  #pragma unroll 8
  for (int i = 0; i < 32; i++){
    const float4 f = w1[i];
    const int e = i * 4;
    #pragma unroll
    for (int r = 0; r < 8; r++)
      acc[r] += s1[r][e]*f.x + s1[r][e+1]*f.y + s1[r][e+2]*f.z + s1[r][e+3]*f.w;
  }
  #pragma unroll 8
  for (int i = 0; i < 32; i++){
    const float4 f = w2[i];
    const int e = i * 4;
    #pragma unroll
    for (int r = 0; r < 8; r++)
      acc[r] += s2[r][e]*f.x + s2[r][e+1]*f.y + s2[r][e+2]*f.z + s2[r][e+3]*f.w;
  }
  const float* wl = Wql + (size_t)d * (DD + 2);
  for (int e = 0; e < DD; e++){
    const float w = wl[e];
    #pragma unroll
    for (int r = 0; r < 8; r++) acc[r] += s3[r][e] * w;
  }
  const float wld = wl[DD], wlf = wl[DD+1];
  #pragma unroll
  for (int r = 0; r < 8; r++){
    const int bp = bp0 + r;
    const float qv = acc[r] + loadv[bp] * wld + leftv[bp] * wlf;
    sq_out[(size_t)bp * DD + d] = 1.f / (1.f + expf(-qv));
  }
}

// ---------------- K2: k,v projections; ekk = [exp(k)*v | exp(k)]. Row-tile 16.
__global__ __launch_bounds__(128) void k_kv(
    const float* __restrict__ nodes, const float* __restrict__ Wk,
    const float* __restrict__ Wv, float* __restrict__ ekk)
{
  __shared__ float ns[16][DD];
  const int d = threadIdx.x;
  const size_t n0 = (size_t)blockIdx.x * 16;
  {
    const float4* g = (const float4*)(nodes + n0 * DD);
    float4* t = (float4*)&ns[0][0];
    #pragma unroll
    for (int k = 0; k < 4; k++){ const int ii = d + k * 128; t[ii] = g[ii]; }
  }
  __syncthreads();
  float ak[16], av[16];
  #pragma unroll
  for (int r = 0; r < 16; r++){ ak[r] = 0.f; av[r] = 0.f; }
  const float4* wk = (const float4*)(Wk + (size_t)d * DD);
  const float4* wv = (const float4*)(Wv + (size_t)d * DD);
  #pragma unroll 4
  for (int i = 0; i < 32; i++){
    const float4 f = wk[i];
    const float4 g = wv[i];
    const int e = i * 4;
    #pragma unroll
    for (int r = 0; r < 16; r++){
      const float n0v = ns[r][e], n1 = ns[r][e+1], n2 = ns[r][e+2], n3 = ns[r][e+3];
      ak[r] += n0v*f.x + n1*f.y + n2*f.z + n3*f.w;
      av[r] += n0v*g.x + n1*g.y + n2*g.z + n3*g.w;
    }
  }
  #pragma unroll
  for (int r = 0; r < 16; r++){
    const float ek = expf(ak[r]);
    float* o = ekk + (n0 + r) * 256;
    o[d]      = ek * av[r];
    o[DD + d] = ek;
  }
}

// ---------------- K3a: partial[ks][b][p][c] = sum_{k in slice ks} ea[p][k] * ekk[k][c]
// ea computed on the fly. Block: 256 thr = (64 col-groups x 4 row-groups),
// thread tile 8p x 4c. grid: (7 mtiles * KSPLIT, B).
__global__ __launch_bounds__(256) void k_aft_gemm(
    const float* __restrict__ dist, const float* __restrict__ ninf,
    const float* __restrict__ ekk, const float* __restrict__ log_scale,
    const float* __restrict__ aft_alpha, float* __restrict__ partial)
{
  __shared__ float Bs[32][256];     // ekk chunk, 32 KB
  __shared__ float As[32][36];      // eaT[k][p] (padded), 4.6 KB
  const int tid = threadIdx.x;
  const int b = blockIdx.y;
  const int m  = blockIdx.x / KSPLIT;   // 0..6
  const int ks = blockIdx.x % KSPLIT;   // 0..3
  const int p0 = m * MT;
  const int k0s = ks * KSLICE;
  const float scale = log_scale[0] * aft_alpha[0];
  const int tx = tid & 63;   // cols tx*4 .. +4
  const int ty = tid >> 6;   // rows ty*8 .. +8
  float acc[8][4];
  #pragma unroll
  for (int i = 0; i < 8; i++)
    #pragma unroll
    for (int j = 0; j < 4; j++) acc[i][j] = 0.f;

  for (int kc = 0; kc < KSLICE; kc += 32){
    const int kend = min(32, KSLICE - kc);   // 32 or 20
    const int kbase = k0s + kc;
    // stage B: ekk rows kbase..kbase+kend (256 cols each)
    {
      const float4* src = (const float4*)(ekk + ((size_t)b * NN + kbase) * 256);
      float4* dst = (float4*)&Bs[0][0];
      #pragma unroll
      for (int j = 0; j < 8; j++){
        const int ii = tid + j * 256;       // float4 index; row = ii>>6
        if ((ii >> 6) < kend) dst[ii] = src[ii];
        else dst[ii] = make_float4(0.f,0.f,0.f,0.f);
      }
    }
    // stage A: eaT[k][p] for 32 p x kend k (transposed, zero-padded)
    {
      const int pl = tid >> 3;          // 0..31
      const int kl = (tid & 7) * 4;     // 0,4,...,28
      const int p  = p0 + pl;
      float e0=0.f, e1=0.f, e2=0.f, e3=0.f;
      if (p < PP){
        const size_t off = ((size_t)b * PP + p) * NN + kbase + kl;
        if (kl + 4 <= kend){
          const float4 dv = *(const float4*)(dist + off);
          const float4 nv = *(const float4*)(ninf + off);
          e0 = expf(nv.x - scale*dv.x);
          e1 = expf(nv.y - scale*dv.y);
          e2 = expf(nv.z - scale*dv.z);
          e3 = expf(nv.w - scale*dv.w);
        } else {
          if (kl+0 < kend) e0 = expf(ninf[off+0] - scale*dist[off+0]);
          if (kl+1 < kend) e1 = expf(ninf[off+1] - scale*dist[off+1]);
          if (kl+2 < kend) e2 = expf(ninf[off+2] - scale*dist[off+2]);
          if (kl+3 < kend) e3 = expf(ninf[off+3] - scale*dist[off+3]);
        }
      }
      As[kl+0][pl] = e0; As[kl+1][pl] = e1; As[kl+2][pl] = e2; As[kl+3][pl] = e3;
    }
    __syncthreads();
    #pragma unroll 4
    for (int k = 0; k < 32; k++){
      const float4 a0 = *(const float4*)&As[k][ty*8];
      const float4 a1 = *(const float4*)&As[k][ty*8+4];
      const float4 bv = *(const float4*)&Bs[k][tx*4];
      acc[0][0]+=a0.x*bv.x; acc[0][1]+=a0.x*bv.y; acc[0][2]+=a0.x*bv.z; acc[0][3]+=a0.x*bv.w;
      acc[1][0]+=a0.y*bv.x; acc[1][1]+=a0.y*bv.y; acc[1][2]+=a0.y*bv.z; acc[1][3]+=a0.y*bv.w;
      acc[2][0]+=a0.z*bv.x; acc[2][1]+=a0.z*bv.y; acc[2][2]+=a0.z*bv.z; acc[2][3]+=a0.z*bv.w;
      acc[3][0]+=a0.w*bv.x; acc[3][1]+=a0.w*bv.y; acc[3][2]+=a0.w*bv.z; acc[3][3]+=a0.w*bv.w;
      acc[4][0]+=a1.x*bv.x; acc[4][1]+=a1.x*bv.y; acc[4][2]+=a1.x*bv.z; acc[4][3]+=a1.x*bv.w;
      acc[5][0]+=a1.y*bv.x; acc[5][1]+=a1.y*bv.y; acc[5][2]+=a1.y*bv.z; acc[5][3]+=a1.y*bv.w;
      acc[6][0]+=a1.z*bv.x; acc[6][1]+=a1.z*bv.y; acc[6][2]+=a1.z*bv.z; acc[6][3]+=a1.z*bv.w;
      acc[7][0]+=a1.w*bv.x; acc[7][1]+=a1.w*bv.y; acc[7][2]+=a1.w*bv.z; acc[7][3]+=a1.w*bv.w;
    }
    __syncthreads();
  }
  float* dst = partial + (((size_t)ks * BB + b) * MPAD + p0) * 256;
  #pragma unroll
  for (int i = 0; i < 8; i++){
    float4 v = make_float4(acc[i][0], acc[i][1], acc[i][2], acc[i][3]);
    *(float4*)&dst[(size_t)(ty*8+i)*256 + tx*4] = v;
  }
}

// ---------------- K3b: reduce partials; aft = sq * bias/(den+eps). grid (PP, BB) x 128.
__global__ __launch_bounds__(128) void k_aft_reduce(
    const float* __restrict__ partial, const float* __restrict__ sq,
    float* __restrict__ aft)
{
  const int c = threadIdx.x;
  const int p = blockIdx.x, b = blockIdx.y;
  const size_t base = ((size_t)b * MPAD + p) * 256;
  float bias = 0.f, den = 0.f;
  #pragma unroll
  for (int ks = 0; ks < KSPLIT; ks++){
    const float* ptr = partial + (size_t)ks * BB * MPAD * 256 + base;
    bias += ptr[c];
    den  += ptr[c + 128];
  }
  const size_t o = ((size_t)b * PP + p) * DD + c;
  aft[o] = sq[o] * (bias / (den + 1e-20f));
}

// ---------------- K4a: score[b][p][n] = 10*tanh(aft.nodes/sqrt(D) - spb*dist) + ninf
// GEMM M=200(pad 208) N=2000(pad 2048) K=128. Block 256 thr: tile 16p x 256n,
// thread 4p x 4n. grid (13*8, B).
__global__ __launch_bounds__(256) void k_score_gemm(
    const float* __restrict__ aft, const float* __restrict__ nodes,
    const float* __restrict__ dist, const float* __restrict__ ninf,
    const float* __restrict__ log_scale, const float* __restrict__ probs_alpha,
    float* __restrict__ score)
{
  __shared__ float aftT[128][20];     // [d][p] padded, 10.24 KB
  __shared__ float ndT[32][260];      // nodesT chunk [d][n] padded, 33.3 KB
  const int tid = threadIdx.x;
  const int b = blockIdx.y;
  const int mt = blockIdx.x >> 3;     // 0..12
  const int nt = blockIdx.x & 7;      // 0..7
  const int p0 = mt * 16;
  const int n0 = nt * 256;
  const float spb = log_scale[0] * probs_alpha[0];
  const float isd = 0.088388347648318447f;  // 1/sqrt(128)
  const int tx = tid & 63;   // cols tx*4..+4
  const int ty = tid >> 6;   // rows ty*4..+4

  // stage aftT (all 128 d)
  {
    const int pl = tid >> 4;          // 0..15
    const int d0 = (tid & 15) * 8;    // 0..120
    float4 v0 = make_float4(0,0,0,0), v1 = make_float4(0,0,0,0);
    if (p0 + pl < PP){
      const float* src = aft + ((size_t)b * PP + p0 + pl) * DD + d0;
      v0 = *(const float4*)src;
      v1 = *(const float4*)(src + 4);
    }
    aftT[d0+0][pl]=v0.x; aftT[d0+1][pl]=v0.y; aftT[d0+2][pl]=v0.z; aftT[d0+3][pl]=v0.w;
    aftT[d0+4][pl]=v1.x; aftT[d0+5][pl]=v1.y; aftT[d0+6][pl]=v1.z; aftT[d0+7][pl]=v1.w;
  }
  float acc[4][4];
  #pragma unroll
  for (int i = 0; i < 4; i++)
    #pragma unroll
    for (int j = 0; j < 4; j++) acc[i][j] = 0.f;

  for (int c = 0; c < 4; c++){        // K chunks of 32
    __syncthreads();                  // covers aftT on first iter, ndT reuse after
    // stage nodesT chunk: d in [c*32, c*32+32), n = n0 + tid
    {
      const int n = n0 + tid;
      float4 r[8];
      if (n < NN){
        const float* src = nodes + ((size_t)b * NN + n) * DD + c * 32;
        #pragma unroll
        for (int j = 0; j < 8; j++) r[j] = *(const float4*)(src + j*4);
      } else {
        #pragma unroll
        for (int j = 0; j < 8; j++) r[j] = make_float4(0,0,0,0);
      }
      #pragma unroll
      for (int j = 0; j < 8; j++){
        ndT[j*4+0][tid] = r[j].x; ndT[j*4+1][tid] = r[j].y;
        ndT[j*4+2][tid] = r[j].z; ndT[j*4+3][tid] = r[j].w;
      }
    }
    __syncthreads();
    #pragma unroll 8
    for (int kk = 0; kk < 32; kk++){
      const int k = c * 32 + kk;
      const float4 a = *(const float4*)&aftT[k][ty*4];
      const float4 bv = *(const float4*)&ndT[kk][tx*4];
      acc[0][0]+=a.x*bv.x; acc[0][1]+=a.x*bv.y; acc[0][2]+=a.x*bv.z; acc[0][3]+=a.x*bv.w;
      acc[1][0]+=a.y*bv.x; acc[1][1]+=a.y*bv.y; acc[1][2]+=a.y*bv.z; acc[1][3]+=a.y*bv.w;
      acc[2][0]+=a.z*bv.x; acc[2][1]+=a.z*bv.y; acc[2][2]+=a.z*bv.z; acc[2][3]+=a.z*bv.w;
      acc[3][0]+=a.w*bv.x; acc[3][1]+=a.w*bv.y; acc[3][2]+=a.w*bv.z; acc[3][3]+=a.w*bv.w;
    }
  }
  // epilogue: tanh + mask, store
  const int n = n0 + tx * 4;
  if (n < NN){
    #pragma unroll
    for (int i = 0; i < 4; i++){
      const int p = p0 + ty * 4 + i;
      if (p < PP){
        const size_t off = ((size_t)b * PP + p) * NN + n;
        const float4 dv = *(const float4*)(dist + off);
        const float4 nv = *(const float4*)(ninf + off);
        float4 s;
        s.x = 10.f * tanhf(acc[i][0]*isd - spb*dv.x) + nv.x;
        s.y = 10.f * tanhf(acc[i][1]*isd - spb*dv.y) + nv.y;
        s.z = 10.f * tanhf(acc[i][2]*isd - spb*dv.z) + nv.z;
        s.w = 10.f * tanhf(acc[i][3]*isd - spb*dv.w) + nv.w;
        *(float4*)(score + off) = s;
      }
    }
  }
}

// ---------------- K4b: row softmax over N. grid (PP/4, BB) x 256.
__global__ __launch_bounds__(256) void k_softmax(
    const float* __restrict__ score, float* __restrict__ out)
{
  __shared__ float s[4][NN];
  __shared__ float red[4][256];
  const int tid = threadIdx.x;
  const int b = blockIdx.y;
  const int p0 = blockIdx.x * 4;
  #pragma unroll
  for (int r = 0; r < 4; r++){
    const float4* src = (const float4*)(score + ((size_t)b * PP + p0 + r) * NN);
    float4* dst = (float4*)&s[r][0];
    for (int i = tid; i < NN/4; i += 256) dst[i] = src[i];
  }
  __syncthreads();
  float mx[4] = {-1e30f,-1e30f,-1e30f,-1e30f};
  for (int n = tid; n < NN; n += 256){
    #pragma unroll
    for (int r = 0; r < 4; r++) mx[r] = fmaxf(mx[r], s[r][n]);
  }
  #pragma unroll
  for (int r = 0; r < 4; r++) red[r][tid] = mx[r];
  __syncthreads();
  for (int st = 128; st > 0; st >>= 1){
    if (tid < st){
      #pragma unroll
      for (int r = 0; r < 4; r++) red[r][tid] = fmaxf(red[r][tid], red[r][tid+st]);
    }
    __syncthreads();
  }
  #pragma unroll
  for (int r = 0; r < 4; r++) mx[r] = red[r][0];
  __syncthreads();
  float ps[4] = {0,0,0,0};
  for (int n = tid; n < NN; n += 256){
    #pragma unroll
    for (int r = 0; r < 4; r++){
      const float e = expf(s[r][n] - mx[r]);
      s[r][n] = e;
      ps[r] += e;
    }
  }
  #pragma unroll
  for (int r = 0; r < 4; r++) red[r][tid] = ps[r];
  __syncthreads();
  for (int st = 128; st > 0; st >>= 1){
    if (tid < st){
      #pragma unroll
      for (int r = 0; r < 4; r++) red[r][tid] += red[r][tid+st];
    }
    __syncthreads();
  }
  float inv[4];
  #pragma unroll
  for (int r = 0; r < 4; r++) inv[r] = 1.f / red[r][0];
  __syncthreads();
  #pragma unroll
  for (int r = 0; r < 4; r++){
    float4* dst = (float4*)(out + ((size_t)b * PP + p0 + r) * NN);
    const float4* srcv = (const float4*)&s[r][0];
    for (int i = tid; i < NN/4; i += 256){
      float4 v = srcv[i];
      v.x *= inv[r]; v.y *= inv[r]; v.z *= inv[r]; v.w *= inv[r];
      dst[i] = v;
    }
  }
}

extern "C" void kernel_launch(void* const* d_in, const int* in_sizes, int n_in,
                              void* d_out, int out_size, void* d_ws, size_t ws_size,
                              hipStream_t stream)
{
  const float* nodes = (const float*)d_in[0];
  const float* last  = (const float*)d_in[1];
  const float* q1    = (const float*)d_in[2];
  const float* q2    = (const float*)d_in[3];
  const float* loadv = (const float*)d_in[4];
  const float* leftv = (const float*)d_in[5];
  const float* dist  = (const float*)d_in[6];
  const float* ninf  = (const float*)d_in[7];
  const float* ls    = (const float*)d_in[8];
  const float* Wq1   = (const float*)d_in[9];
  const float* Wq2   = (const float*)d_in[10];
  const float* Wql   = (const float*)d_in[11];
  const float* Wk    = (const float*)d_in[12];
  const float* Wv    = (const float*)d_in[13];
  const float* aa    = (const float*)d_in[14];
  const float* pa    = (const float*)d_in[15];
  float* out = (float*)d_out;

  float* sq      = (float*)d_ws;
  float* ekk     = sq + (size_t)BB * PP * DD;                 // +409600
  float* aft     = ekk + (size_t)BB * NN * 256;               // +8192000
  float* partial = aft + (size_t)BB * PP * DD;                // +409600
  float* score   = partial;                                   // overlap (partials dead)

  k_qproj<<<dim3((BB * PP) / 8), dim3(128), 0, stream>>>(q1, q2, last, loadv, leftv, Wq1, Wq2, Wql, sq);
  k_kv<<<dim3((BB * NN) / 16), dim3(128), 0, stream>>>(nodes, Wk, Wv, ekk);
  k_aft_gemm<<<dim3(7 * KSPLIT, BB), dim3(256), 0, stream>>>(dist, ninf, ekk, ls, aa, partial);
  k_aft_reduce<<<dim3(PP, BB), dim3(128), 0, stream>>>(partial, sq, aft);
  k_score_gemm<<<dim3(13 * 8, BB), dim3(256), 0, stream>>>(aft, nodes, dist, ninf, ls, pa, score);
  k_softmax<<<dim3(PP / 4, BB), dim3(256), 0, stream>>>(score, out);
}

// Round 5
// 230.240 us; speedup vs baseline: 1.7194x; 1.0036x over previous
//
#include <hip/hip_runtime.h>
#include <hip/hip_bf16.h>

// CVRPModel: B=16, P=200, N=2000, D=128. Inputs f32, output f32.
// ws (floats): sq[409600] | ekk[8192000] | aft[409600] | partial[10*16*224*256]
//   score[16*200*2000] overlaps partial (partials dead after k_aft_reduce).
// max(partial 36.7MB, score 51.2MB) = 51.2 -> total ~88 MB (same as round 4).

#define BB 16
#define PP 200
#define NN 2000
#define DD 128
#define KSPLIT 10
#define KSLICE 200          // NN / KSPLIT
#define KCHUNK 25           // KSLICE = 8 * KCHUNK, no tails
#define MT 32               // p-tile in k_aft_gemm
#define MPAD 224            // 7 * 32

// ---------------- K1: q projections + sigmoid
__global__ __launch_bounds__(128) void k_qproj(
    const float* __restrict__ q1, const float* __restrict__ q2,
    const float* __restrict__ last, const float* __restrict__ loadv,
    const float* __restrict__ leftv, const float* __restrict__ Wq1,
    const float* __restrict__ Wq2, const float* __restrict__ Wql,
    float* __restrict__ sq_out)
{
  __shared__ float s1[8][DD], s2[8][DD], s3[8][DD];
  const int d = threadIdx.x;
  const int bp0 = blockIdx.x * 8;
  {
    const float4* g1 = (const float4*)(q1 + (size_t)bp0 * DD);
    const float4* g2 = (const float4*)(q2 + (size_t)bp0 * DD);
    const float4* g3 = (const float4*)(last + (size_t)bp0 * DD);
    float4* t1 = (float4*)&s1[0][0];
    float4* t2 = (float4*)&s2[0][0];
    float4* t3 = (float4*)&s3[0][0];
    #pragma unroll
    for (int k = 0; k < 2; k++){
      const int ii = d + k * 128;
      t1[ii] = g1[ii]; t2[ii] = g2[ii]; t3[ii] = g3[ii];
    }
  }
  __syncthreads();
  float acc[8] = {0,0,0,0,0,0,0,0};
  const float4* w1 = (const float4*)(Wq1 + (size_t)d * DD);
  const float4* w2 = (const float4*)(Wq2 + (size_t)d * DD);
  #pragma unroll 8
  for (int i = 0; i < 32; i++){
    const float4 f = w1[i];
    const int e = i * 4;
    #pragma unroll
    for (int r = 0; r < 8; r++)
      acc[r] += s1[r][e]*f.x + s1[r][e+1]*f.y + s1[r][e+2]*f.z + s1[r][e+3]*f.w;
  }
  #pragma unroll 8
  for (int i = 0; i < 32; i++){
    const float4 f = w2[i];
    const int e = i * 4;
    #pragma unroll
    for (int r = 0; r < 8; r++)
      acc[r] += s2[r][e]*f.x + s2[r][e+1]*f.y + s2[r][e+2]*f.z + s2[r][e+3]*f.w;
  }
  const float* wl = Wql + (size_t)d * (DD + 2);
  for (int e = 0; e < DD; e++){
    const float w = wl[e];
    #pragma unroll
    for (int r = 0; r < 8; r++) acc[r] += s3[r][e] * w;
  }
  const float wld = wl[DD], wlf = wl[DD+1];
  #pragma unroll
  for (int r = 0; r < 8; r++){
    const int bp = bp0 + r;
    const float qv = acc[r] + loadv[bp] * wld + leftv[bp] * wlf;
    sq_out[(size_t)bp * DD + d] = 1.f / (1.f + expf(-qv));
  }
}

// ---------------- K2: k,v projections; ekk = [exp(k)*v | exp(k)]. Row-tile 16.
__global__ __launch_bounds__(128) void k_kv(
    const float* __restrict__ nodes, const float* __restrict__ Wk,
    const float* __restrict__ Wv, float* __restrict__ ekk)
{
  __shared__ float ns[16][DD];
  const int d = threadIdx.x;
  const size_t n0 = (size_t)blockIdx.x * 16;
  {
    const float4* g = (const float4*)(nodes + n0 * DD);
    float4* t = (float4*)&ns[0][0];
    #pragma unroll
    for (int k = 0; k < 4; k++){ const int ii = d + k * 128; t[ii] = g[ii]; }
  }
  __syncthreads();
  float ak[16], av[16];
  #pragma unroll
  for (int r = 0; r < 16; r++){ ak[r] = 0.f; av[r] = 0.f; }
  const float4* wk = (const float4*)(Wk + (size_t)d * DD);
  const float4* wv = (const float4*)(Wv + (size_t)d * DD);
  #pragma unroll 4
  for (int i = 0; i < 32; i++){
    const float4 f = wk[i];
    const float4 g = wv[i];
    const int e = i * 4;
    #pragma unroll
    for (int r = 0; r < 16; r++){
      const float n0v = ns[r][e], n1 = ns[r][e+1], n2 = ns[r][e+2], n3 = ns[r][e+3];
      ak[r] += n0v*f.x + n1*f.y + n2*f.z + n3*f.w;
      av[r] += n0v*g.x + n1*g.y + n2*g.z + n3*g.w;
    }
  }
  #pragma unroll
  for (int r = 0; r < 16; r++){
    const float ek = expf(ak[r]);
    float* o = ekk + (n0 + r) * 256;
    o[d]      = ek * av[r];
    o[DD + d] = ek;
  }
}

// ---------------- K3a: partial[ks][b][p][c] = sum_{k in slice ks} ea[p][k] * ekk[k][c]
// Block 256 thr = 64 col-groups x 4 row-groups; thread tile 8p x 4c.
// grid: (7 mtiles * KSPLIT, B). KSLICE=200 = 8 chunks of 25 (no tails).
__global__ __launch_bounds__(256) void k_aft_gemm(
    const float* __restrict__ dist, const float* __restrict__ ninf,
    const float* __restrict__ ekk, const float* __restrict__ log_scale,
    const float* __restrict__ aft_alpha, float* __restrict__ partial)
{
  __shared__ float Bs[KCHUNK][256];     // ekk chunk, 25.6 KB
  __shared__ float As[KCHUNK][36];      // eaT[k][p] padded, 3.6 KB
  const int tid = threadIdx.x;
  const int b = blockIdx.y;
  const int m  = blockIdx.x / KSPLIT;   // 0..6
  const int ks = blockIdx.x % KSPLIT;   // 0..9
  const int p0 = m * MT;
  const int k0s = ks * KSLICE;
  const float scale = log_scale[0] * aft_alpha[0];
  const int tx = tid & 63;   // cols tx*4 .. +4
  const int ty = tid >> 6;   // rows ty*8 .. +8
  float acc[8][4];
  #pragma unroll
  for (int i = 0; i < 8; i++)
    #pragma unroll
    for (int j = 0; j < 4; j++) acc[i][j] = 0.f;

  for (int c = 0; c < KSLICE / KCHUNK; c++){
    const int kbase = k0s + c * KCHUNK;
    // stage B: 25 rows x 256 cols = 1600 float4
    {
      const float4* src = (const float4*)(ekk + ((size_t)b * NN + kbase) * 256);
      float4* dst = (float4*)&Bs[0][0];
      for (int ii = tid; ii < KCHUNK * 64; ii += 256) dst[ii] = src[ii];
    }
    // stage A: eaT[k][p] for 32 p x 25 k (transposed)
    {
      const int pl = tid >> 3;          // 0..31
      const int kl = (tid & 7) * 4;     // 0,4,...,28
      const int p  = p0 + pl;
      if (kl < KCHUNK){
        float e0=0.f, e1=0.f, e2=0.f, e3=0.f;
        if (p < PP){
          const size_t off = ((size_t)b * PP + p) * NN + kbase + kl;
          if (kl + 4 <= KCHUNK){
            const float4 dv = *(const float4*)(dist + off);
            const float4 nv = *(const float4*)(ninf + off);
            e0 = expf(nv.x - scale*dv.x);
            e1 = expf(nv.y - scale*dv.y);
            e2 = expf(nv.z - scale*dv.z);
            e3 = expf(nv.w - scale*dv.w);
          } else {
            e0 = expf(ninf[off] - scale*dist[off]);   // kl==24: one valid k
          }
        }
        As[kl][pl] = e0;
        if (kl + 4 <= KCHUNK){
          As[kl+1][pl] = e1; As[kl+2][pl] = e2; As[kl+3][pl] = e3;
        }
      }
    }
    __syncthreads();
    #pragma unroll 5
    for (int k = 0; k < KCHUNK; k++){
      const float4 a0 = *(const float4*)&As[k][ty*8];
      const float4 a1 = *(const float4*)&As[k][ty*8+4];
      const float4 bv = *(const float4*)&Bs[k][tx*4];
      acc[0][0]+=a0.x*bv.x; acc[0][1]+=a0.x*bv.y; acc[0][2]+=a0.x*bv.z; acc[0][3]+=a0.x*bv.w;
      acc[1][0]+=a0.y*bv.x; acc[1][1]+=a0.y*bv.y; acc[1][2]+=a0.y*bv.z; acc[1][3]+=a0.y*bv.w;
      acc[2][0]+=a0.z*bv.x; acc[2][1]+=a0.z*bv.y; acc[2][2]+=a0.z*bv.z; acc[2][3]+=a0.z*bv.w;
      acc[3][0]+=a0.w*bv.x; acc[3][1]+=a0.w*bv.y; acc[3][2]+=a0.w*bv.z; acc[3][3]+=a0.w*bv.w;
      acc[4][0]+=a1.x*bv.x; acc[4][1]+=a1.x*bv.y; acc[4][2]+=a1.x*bv.z; acc[4][3]+=a1.x*bv.w;
      acc[5][0]+=a1.y*bv.x; acc[5][1]+=a1.y*bv.y; acc[5][2]+=a1.y*bv.z; acc[5][3]+=a1.y*bv.w;
      acc[6][0]+=a1.z*bv.x; acc[6][1]+=a1.z*bv.y; acc[6][2]+=a1.z*bv.z; acc[6][3]+=a1.z*bv.w;
      acc[7][0]+=a1.w*bv.x; acc[7][1]+=a1.w*bv.y; acc[7][2]+=a1.w*bv.z; acc[7][3]+=a1.w*bv.w;
    }
    __syncthreads();
  }
  float* dst = partial + (((size_t)ks * BB + b) * MPAD + p0) * 256;
  #pragma unroll
  for (int i = 0; i < 8; i++){
    float4 v = make_float4(acc[i][0], acc[i][1], acc[i][2], acc[i][3]);
    *(float4*)&dst[(size_t)(ty*8+i)*256 + tx*4] = v;
  }
}

// ---------------- K3b: reduce partials; aft = sq * bias/(den+eps).
// grid (25, BB) x 256: block handles 8 p rows (2 at a time).
__global__ __launch_bounds__(256) void k_aft_reduce(
    const float* __restrict__ partial, const float* __restrict__ sq,
    float* __restrict__ aft)
{
  const int pl = threadIdx.x >> 7;        // 0..1
  const int c  = threadIdx.x & 127;
  const int b = blockIdx.y;
  #pragma unroll
  for (int i = 0; i < 4; i++){
    const int p = blockIdx.x * 8 + i * 2 + pl;
    const size_t base = ((size_t)b * MPAD + p) * 256;
    float bias = 0.f, den = 0.f;
    #pragma unroll
    for (int ks = 0; ks < KSPLIT; ks++){
      const float* ptr = partial + (size_t)ks * BB * MPAD * 256 + base;
      bias += ptr[c];
      den  += ptr[c + 128];
    }
    const size_t o = ((size_t)b * PP + p) * DD + c;
    aft[o] = sq[o] * (bias / (den + 1e-20f));
  }
}

// ---------------- K4a: score = 10*tanh(aft.nodes/sqrt(D) - spb*dist) + ninf
// GEMM M=200(pad 208) N=2000(pad 2048) K=128. Block 256: tile 16p x 256n,
// thread 4p x 4n. grid (13*8, B).
__global__ __launch_bounds__(256) void k_score_gemm(
    const float* __restrict__ aft, const float* __restrict__ nodes,
    const float* __restrict__ dist, const float* __restrict__ ninf,
    const float* __restrict__ log_scale, const float* __restrict__ probs_alpha,
    float* __restrict__ score)
{
  __shared__ float aftT[128][20];     // [d][p] padded
  __shared__ float ndT[32][260];      // nodesT chunk [d][n] padded
  const int tid = threadIdx.x;
  const int b = blockIdx.y;
  const int mt = blockIdx.x >> 3;     // 0..12
  const int nt = blockIdx.x & 7;      // 0..7
  const int p0 = mt * 16;
  const int n0 = nt * 256;
  const float spb = log_scale[0] * probs_alpha[0];
  const float isd = 0.088388347648318447f;  // 1/sqrt(128)
  const int tx = tid & 63;
  const int ty = tid >> 6;

  {
    const int pl = tid >> 4;
    const int d0 = (tid & 15) * 8;
    float4 v0 = make_float4(0,0,0,0), v1 = make_float4(0,0,0,0);
    if (p0 + pl < PP){
      const float* src = aft + ((size_t)b * PP + p0 + pl) * DD + d0;
      v0 = *(const float4*)src;
      v1 = *(const float4*)(src + 4);
    }
    aftT[d0+0][pl]=v0.x; aftT[d0+1][pl]=v0.y; aftT[d0+2][pl]=v0.z; aftT[d0+3][pl]=v0.w;
    aftT[d0+4][pl]=v1.x; aftT[d0+5][pl]=v1.y; aftT[d0+6][pl]=v1.z; aftT[d0+7][pl]=v1.w;
  }
  float acc[4][4];
  #pragma unroll
  for (int i = 0; i < 4; i++)
    #pragma unroll
    for (int j = 0; j < 4; j++) acc[i][j] = 0.f;

  for (int c = 0; c < 4; c++){
    __syncthreads();
    {
      const int n = n0 + tid;
      float4 r[8];
      if (n < NN){
        const float* src = nodes + ((size_t)b * NN + n) * DD + c * 32;
        #pragma unroll
        for (int j = 0; j < 8; j++) r[j] = *(const float4*)(src + j*4);
      } else {
        #pragma unroll
        for (int j = 0; j < 8; j++) r[j] = make_float4(0,0,0,0);
      }
      #pragma unroll
      for (int j = 0; j < 8; j++){
        ndT[j*4+0][tid] = r[j].x; ndT[j*4+1][tid] = r[j].y;
        ndT[j*4+2][tid] = r[j].z; ndT[j*4+3][tid] = r[j].w;
      }
    }
    __syncthreads();
    #pragma unroll 8
    for (int kk = 0; kk < 32; kk++){
      const int k = c * 32 + kk;
      const float4 a = *(const float4*)&aftT[k][ty*4];
      const float4 bv = *(const float4*)&ndT[kk][tx*4];
      acc[0][0]+=a.x*bv.x; acc[0][1]+=a.x*bv.y; acc[0][2]+=a.x*bv.z; acc[0][3]+=a.x*bv.w;
      acc[1][0]+=a.y*bv.x; acc[1][1]+=a.y*bv.y; acc[1][2]+=a.y*bv.z; acc[1][3]+=a.y*bv.w;
      acc[2][0]+=a.z*bv.x; acc[2][1]+=a.z*bv.y; acc[2][2]+=a.z*bv.z; acc[2][3]+=a.z*bv.w;
      acc[3][0]+=a.w*bv.x; acc[3][1]+=a.w*bv.y; acc[3][2]+=a.w*bv.z; acc[3][3]+=a.w*bv.w;
    }
  }
  const int n = n0 + tx * 4;
  if (n < NN){
    #pragma unroll
    for (int i = 0; i < 4; i++){
      const int p = p0 + ty * 4 + i;
      if (p < PP){
        const size_t off = ((size_t)b * PP + p) * NN + n;
        const float4 dv = *(const float4*)(dist + off);
        const float4 nv = *(const float4*)(ninf + off);
        float4 s;
        s.x = 10.f * tanhf(acc[i][0]*isd - spb*dv.x) + nv.x;
        s.y = 10.f * tanhf(acc[i][1]*isd - spb*dv.y) + nv.y;
        s.z = 10.f * tanhf(acc[i][2]*isd - spb*dv.z) + nv.z;
        s.w = 10.f * tanhf(acc[i][3]*isd - spb*dv.w) + nv.w;
        *(float4*)(score + off) = s;
      }
    }
  }
}

// ---------------- K4b: row softmax over N. grid (PP/4, BB) x 256.
__global__ __launch_bounds__(256) void k_softmax(
    const float* __restrict__ score, float* __restrict__ out)
{
  __shared__ float s[4][NN];
  __shared__ float red[4][256];
  const int tid = threadIdx.x;
  const int b = blockIdx.y;
  const int p0 = blockIdx.x * 4;
  #pragma unroll
  for (int r = 0; r < 4; r++){
    const float4* src = (const float4*)(score + ((size_t)b * PP + p0 + r) * NN);
    float4* dst = (float4*)&s[r][0];
    for (int i = tid; i < NN/4; i += 256) dst[i] = src[i];
  }
  __syncthreads();
  float mx[4] = {-1e30f,-1e30f,-1e30f,-1e30f};
  for (int n = tid; n < NN; n += 256){
    #pragma unroll
    for (int r = 0; r < 4; r++) mx[r] = fmaxf(mx[r], s[r][n]);
  }
  #pragma unroll
  for (int r = 0; r < 4; r++) red[r][tid] = mx[r];
  __syncthreads();
  for (int st = 128; st > 0; st >>= 1){
    if (tid < st){
      #pragma unroll
      for (int r = 0; r < 4; r++) red[r][tid] = fmaxf(red[r][tid], red[r][tid+st]);
    }
    __syncthreads();
  }
  #pragma unroll
  for (int r = 0; r < 4; r++) mx[r] = red[r][0];
  __syncthreads();
  float ps[4] = {0,0,0,0};
  for (int n = tid; n < NN; n += 256){
    #pragma unroll
    for (int r = 0; r < 4; r++){
      const float e = expf(s[r][n] - mx[r]);
      s[r][n] = e;
      ps[r] += e;
    }
  }
  #pragma unroll
  for (int r = 0; r < 4; r++) red[r][tid] = ps[r];
  __syncthreads();
  for (int st = 128; st > 0; st >>= 1){
    if (tid < st){
      #pragma unroll
      for (int r = 0; r < 4; r++) red[r][tid] += red[r][tid+st];
    }
    __syncthreads();
  }
  float inv[4];
  #pragma unroll
  for (int r = 0; r < 4; r++) inv[r] = 1.f / red[r][0];
  __syncthreads();
  #pragma unroll
  for (int r = 0; r < 4; r++){
    float4* dst = (float4*)(out + ((size_t)b * PP + p0 + r) * NN);
    const float4* srcv = (const float4*)&s[r][0];
    for (int i = tid; i < NN/4; i += 256){
      float4 v = srcv[i];
      v.x *= inv[r]; v.y *= inv[r]; v.z *= inv[r]; v.w *= inv[r];
      dst[i] = v;
    }
  }
}

extern "C" void kernel_launch(void* const* d_in, const int* in_sizes, int n_in,
                              void* d_out, int out_size, void* d_ws, size_t ws_size,
                              hipStream_t stream)
{
  const float* nodes = (const float*)d_in[0];
  const float* last  = (const float*)d_in[1];
  const float* q1    = (const float*)d_in[2];
  const float* q2    = (const float*)d_in[3];
  const float* loadv = (const float*)d_in[4];
  const float* leftv = (const float*)d_in[5];
  const float* dist  = (const float*)d_in[6];
  const float* ninf  = (const float*)d_in[7];
  const float* ls    = (const float*)d_in[8];
  const float* Wq1   = (const float*)d_in[9];
  const float* Wq2   = (const float*)d_in[10];
  const float* Wql   = (const float*)d_in[11];
  const float* Wk    = (const float*)d_in[12];
  const float* Wv    = (const float*)d_in[13];
  const float* aa    = (const float*)d_in[14];
  const float* pa    = (const float*)d_in[15];
  float* out = (float*)d_out;

  float* sq      = (float*)d_ws;
  float* ekk     = sq + (size_t)BB * PP * DD;                 // +409600
  float* aft     = ekk + (size_t)BB * NN * 256;               // +8192000
  float* partial = aft + (size_t)BB * PP * DD;                // +409600
  float* score   = partial;                                   // overlap (partials dead)

  k_qproj<<<dim3((BB * PP) / 8), dim3(128), 0, stream>>>(q1, q2, last, loadv, leftv, Wq1, Wq2, Wql, sq);
  k_kv<<<dim3((BB * NN) / 16), dim3(128), 0, stream>>>(nodes, Wk, Wv, ekk);
  k_aft_gemm<<<dim3(7 * KSPLIT, BB), dim3(256), 0, stream>>>(dist, ninf, ekk, ls, aa, partial);
  k_aft_reduce<<<dim3(25, BB), dim3(256), 0, stream>>>(partial, sq, aft);
  k_score_gemm<<<dim3(13 * 8, BB), dim3(256), 0, stream>>>(aft, nodes, dist, ninf, ls, pa, score);
  k_softmax<<<dim3(PP / 4, BB), dim3(256), 0, stream>>>(score, out);
}

// Round 6
// 212.157 us; speedup vs baseline: 1.8660x; 1.0852x over previous
//
#include <hip/hip_runtime.h>
#include <hip/hip_bf16.h>

// CVRPModel: B=16, P=200, N=2000, D=128. Inputs f32, output f32.
// Round 6: k_aft via split-bf16 (hi+lo) MFMA, 3-pass -> ~f32 precision.
// ws bytes: sq f32 @0 (1.6384MB) | aft f32 @1638400 | ekkT_hi bf16 @3276800
//   (16.78MB, [b][c:256][k:2048]) | ekkT_lo @20054016 | partial f32 @36831232
//   ([8][16][256][256], 33.55MB; score 25.6MB overlaps partial). total 70.4MB.

#define BB 16
#define PP 200
#define NN 2000
#define DD 128
#define KPAD 2048

typedef __attribute__((ext_vector_type(8))) short short8;
typedef __attribute__((ext_vector_type(4))) float f32x4;
typedef unsigned short ushort_t;

__device__ __forceinline__ ushort_t f2bf(float x){
  union{float f; unsigned int u;} v; v.f = x;
  unsigned int r = v.u + 0x7fffu + ((v.u >> 16) & 1u);
  return (ushort_t)(r >> 16);
}
__device__ __forceinline__ float bf2f(ushort_t h){
  union{unsigned int u; float f;} v; v.u = ((unsigned int)h) << 16; return v.f;
}

// ---------------- K1: q projections + sigmoid (unchanged, passing)
__global__ __launch_bounds__(128) void k_qproj(
    const float* __restrict__ q1, const float* __restrict__ q2,
    const float* __restrict__ last, const float* __restrict__ loadv,
    const float* __restrict__ leftv, const float* __restrict__ Wq1,
    const float* __restrict__ Wq2, const float* __restrict__ Wql,
    float* __restrict__ sq_out)
{
  __shared__ float s1[8][DD], s2[8][DD], s3[8][DD];
  const int d = threadIdx.x;
  const int bp0 = blockIdx.x * 8;
  {
    const float4* g1 = (const float4*)(q1 + (size_t)bp0 * DD);
    const float4* g2 = (const float4*)(q2 + (size_t)bp0 * DD);
    const float4* g3 = (const float4*)(last + (size_t)bp0 * DD);
    float4* t1 = (float4*)&s1[0][0];
    float4* t2 = (float4*)&s2[0][0];
    float4* t3 = (float4*)&s3[0][0];
    #pragma unroll
    for (int k = 0; k < 2; k++){
      const int ii = d + k * 128;
      t1[ii] = g1[ii]; t2[ii] = g2[ii]; t3[ii] = g3[ii];
    }
  }
  __syncthreads();
  float acc[8] = {0,0,0,0,0,0,0,0};
  const float4* w1 = (const float4*)(Wq1 + (size_t)d * DD);
  const float4* w2 = (const float4*)(Wq2 + (size_t)d * DD);
  #pragma unroll 8
  for (int i = 0; i < 32; i++){
    const float4 f = w1[i];
    const int e = i * 4;
    #pragma unroll
    for (int r = 0; r < 8; r++)
      acc[r] += s1[r][e]*f.x + s1[r][e+1]*f.y + s1[r][e+2]*f.z + s1[r][e+3]*f.w;
  }
  #pragma unroll 8
  for (int i = 0; i < 32; i++){
    const float4 f = w2[i];
    const int e = i * 4;
    #pragma unroll
    for (int r = 0; r < 8; r++)
      acc[r] += s2[r][e]*f.x + s2[r][e+1]*f.y + s2[r][e+2]*f.z + s2[r][e+3]*f.w;
  }
  const float* wl = Wql + (size_t)d * (DD + 2);
  for (int e = 0; e < DD; e++){
    const float w = wl[e];
    #pragma unroll
    for (int r = 0; r < 8; r++) acc[r] += s3[r][e] * w;
  }
  const float wld = wl[DD], wlf = wl[DD+1];
  #pragma unroll
  for (int r = 0; r < 8; r++){
    const int bp = bp0 + r;
    const float qv = acc[r] + loadv[bp] * wld + leftv[bp] * wlf;
    sq_out[(size_t)bp * DD + d] = 1.f / (1.f + expf(-qv));
  }
}

// ---------------- K2: k,v projections; ekkT planes (bf16 hi/lo), transposed + k-padded.
// ekkT[b][c][k]: c<128 -> exp(k)*v col, c>=128 -> exp(k) col. grid (128, B) x 128.
__global__ __launch_bounds__(128) void k_kv(
    const float* __restrict__ nodes, const float* __restrict__ Wk,
    const float* __restrict__ Wv, ushort_t* __restrict__ ekkT_hi,
    ushort_t* __restrict__ ekkT_lo)
{
  __shared__ float ns[16][DD];
  __shared__ float st[256][17];          // [c][n] padded (+1 f32 -> conflict-free)
  const int d = threadIdx.x;
  const int b = blockIdx.y;
  const int n0 = blockIdx.x * 16;

  if (n0 < NN){
    const float4* g = (const float4*)(nodes + ((size_t)b * NN + n0) * DD);
    float4* t = (float4*)&ns[0][0];
    #pragma unroll
    for (int k = 0; k < 4; k++){ const int ii = d + k * 128; t[ii] = g[ii]; }
    __syncthreads();
    float ak[16], av[16];
    #pragma unroll
    for (int r = 0; r < 16; r++){ ak[r] = 0.f; av[r] = 0.f; }
    const float4* wk = (const float4*)(Wk + (size_t)d * DD);
    const float4* wv = (const float4*)(Wv + (size_t)d * DD);
    #pragma unroll 4
    for (int i = 0; i < 32; i++){
      const float4 f = wk[i];
      const float4 g2 = wv[i];
      const int e = i * 4;
      #pragma unroll
      for (int r = 0; r < 16; r++){
        const float n0v = ns[r][e], n1 = ns[r][e+1], n2 = ns[r][e+2], n3 = ns[r][e+3];
        ak[r] += n0v*f.x + n1*f.y + n2*f.z + n3*f.w;
        av[r] += n0v*g2.x + n1*g2.y + n2*g2.z + n3*g2.w;
      }
    }
    #pragma unroll
    for (int r = 0; r < 16; r++){
      const float ek = expf(ak[r]);
      st[d][r]      = ek * av[r];
      st[DD + d][r] = ek;
    }
    __syncthreads();
  }
  // transposed write-out: thread handles columns d and d+128; 16 n each.
  #pragma unroll
  for (int cc = 0; cc < 2; cc++){
    const int c = d + cc * 128;
    unsigned int oh[8], ol[8];
    if (n0 < NN){
      #pragma unroll
      for (int j = 0; j < 8; j++){
        const float x0 = st[c][2*j], x1 = st[c][2*j+1];
        const ushort_t h0 = f2bf(x0), h1 = f2bf(x1);
        const ushort_t l0 = f2bf(x0 - bf2f(h0)), l1 = f2bf(x1 - bf2f(h1));
        oh[j] = (unsigned int)h0 | ((unsigned int)h1 << 16);
        ol[j] = (unsigned int)l0 | ((unsigned int)l1 << 16);
      }
    } else {
      #pragma unroll
      for (int j = 0; j < 8; j++){ oh[j] = 0u; ol[j] = 0u; }
    }
    ushort_t* dh = ekkT_hi + ((size_t)b * 256 + c) * KPAD + n0;
    ushort_t* dl = ekkT_lo + ((size_t)b * 256 + c) * KPAD + n0;
    *(uint4*)dh       = make_uint4(oh[0], oh[1], oh[2], oh[3]);
    *((uint4*)dh + 1) = make_uint4(oh[4], oh[5], oh[6], oh[7]);
    *(uint4*)dl       = make_uint4(ol[0], ol[1], ol[2], ol[3]);
    *((uint4*)dl + 1) = make_uint4(ol[4], ol[5], ol[6], ol[7]);
  }
}

// ---------------- K3a: partial[ks][b][p][c] = sum_k ea[p][k] * ekkT[c][k]
// split-bf16 3-pass MFMA (hi*hi + hi*lo + lo*hi). Block 512 thr = 8 waves,
// tile 64p x 256c; wave = 32p x 64c = 2x4 16x16 tiles. grid (4mi*8ks, B).
__global__ __launch_bounds__(512) void k_aft_mfma(
    const float* __restrict__ dist, const float* __restrict__ ninf,
    const ushort_t* __restrict__ ekkT_hi, const ushort_t* __restrict__ ekkT_lo,
    const float* __restrict__ log_scale, const float* __restrict__ aft_alpha,
    float* __restrict__ partial)
{
  __shared__ __align__(16) ushort_t ea_hi[64][40];  // [p][k] per 32-k chunk, pad 8
  __shared__ __align__(16) ushort_t ea_lo[64][40];
  const int tid = threadIdx.x;
  const int b = blockIdx.y;
  const int mi = blockIdx.x >> 3;      // 0..3  -> p0
  const int ks = blockIdx.x & 7;       // 0..7  -> k slice of 256
  const int p0 = mi * 64;
  const int k0 = ks * 256;
  const float scale = log_scale[0] * aft_alpha[0];
  const int w  = tid >> 6;
  const int l  = tid & 63;
  const int wp = w >> 2;               // 0..1
  const int wc = w & 3;                // 0..3
  const int lr = l & 15;
  const int lk = (l >> 4) * 8;

  f32x4 acc[2][4];
  #pragma unroll
  for (int i = 0; i < 2; i++)
    #pragma unroll
    for (int j = 0; j < 4; j++) acc[i][j] = (f32x4){0.f, 0.f, 0.f, 0.f};

  const ushort_t* bptr_h[4];
  const ushort_t* bptr_l[4];
  #pragma unroll
  for (int tc = 0; tc < 4; tc++){
    const int c = wc * 64 + tc * 16 + lr;
    const size_t off = ((size_t)b * 256 + c) * KPAD + k0 + lk;
    bptr_h[tc] = ekkT_hi + off;
    bptr_l[tc] = ekkT_lo + off;
  }

  for (int kc = 0; kc < 8; kc++){
    // B fragments for this chunk (independent of LDS staging -> overlaps exp)
    short8 bh[4], bl[4];
    #pragma unroll
    for (int tc = 0; tc < 4; tc++){
      bh[tc] = *(const short8*)bptr_h[tc];
      bl[tc] = *(const short8*)bptr_l[tc];
      bptr_h[tc] += 32; bptr_l[tc] += 32;
    }
    // stage ea (64p x 32k) as bf16 hi/lo
    int idx = tid;
    #pragma unroll
    for (int i = 0; i < 4; i++){
      const int pl = idx >> 5, kk = idx & 31;
      const int p = p0 + pl, kg = k0 + kc * 32 + kk;
      float e = 0.f;
      if (p < PP && kg < NN){
        const size_t o = ((size_t)b * PP + p) * NN + kg;
        e = expf(ninf[o] - scale * dist[o]);
      }
      const ushort_t h = f2bf(e);
      ea_hi[pl][kk] = h;
      ea_lo[pl][kk] = f2bf(e - bf2f(h));
      idx += 512;
    }
    __syncthreads();
    short8 ah[2], al[2];
    #pragma unroll
    for (int tp = 0; tp < 2; tp++){
      const int row = wp * 32 + tp * 16 + lr;
      ah[tp] = *(const short8*)&ea_hi[row][lk];
      al[tp] = *(const short8*)&ea_lo[row][lk];
    }
    #pragma unroll
    for (int tp = 0; tp < 2; tp++)
      #pragma unroll
      for (int tc = 0; tc < 4; tc++){
        acc[tp][tc] = __builtin_amdgcn_mfma_f32_16x16x32_bf16(ah[tp], bh[tc], acc[tp][tc], 0, 0, 0);
        acc[tp][tc] = __builtin_amdgcn_mfma_f32_16x16x32_bf16(ah[tp], bl[tc], acc[tp][tc], 0, 0, 0);
        acc[tp][tc] = __builtin_amdgcn_mfma_f32_16x16x32_bf16(al[tp], bh[tc], acc[tp][tc], 0, 0, 0);
      }
    __syncthreads();
  }
  // store: C/D layout col=lane&15, row=(lane>>4)*4+reg  [m89-verified]
  #pragma unroll
  for (int tp = 0; tp < 2; tp++){
    const int prow = p0 + wp * 32 + tp * 16 + (l >> 4) * 4;
    #pragma unroll
    for (int tc = 0; tc < 4; tc++){
      const int c = wc * 64 + tc * 16 + (l & 15);
      #pragma unroll
      for (int r = 0; r < 4; r++){
        partial[(size_t)ks * 1048576 + ((size_t)b * 256 + prow + r) * 256 + c] = acc[tp][tc][r];
      }
    }
  }
}

// ---------------- K3b: reduce 8 partials; aft = sq * bias/(den+eps). grid (25,B) x 256.
__global__ __launch_bounds__(256) void k_aft_reduce(
    const float* __restrict__ partial, const float* __restrict__ sq,
    float* __restrict__ aft)
{
  const int pl = threadIdx.x >> 7;
  const int c  = threadIdx.x & 127;
  const int b = blockIdx.y;
  #pragma unroll
  for (int i = 0; i < 4; i++){
    const int p = blockIdx.x * 8 + i * 2 + pl;
    const size_t base = ((size_t)b * 256 + p) * 256;
    float bias = 0.f, den = 0.f;
    #pragma unroll
    for (int ksi = 0; ksi < 8; ksi++){
      const float* ptr = partial + (size_t)ksi * 1048576 + base;
      bias += ptr[c];
      den  += ptr[c + 128];
    }
    const size_t o = ((size_t)b * PP + p) * DD + c;
    aft[o] = sq[o] * (bias / (den + 1e-20f));
  }
}

// ---------------- K4a: score GEMM + tanh epilogue (unchanged)
__global__ __launch_bounds__(256) void k_score_gemm(
    const float* __restrict__ aft, const float* __restrict__ nodes,
    const float* __restrict__ dist, const float* __restrict__ ninf,
    const float* __restrict__ log_scale, const float* __restrict__ probs_alpha,
    float* __restrict__ score)
{
  __shared__ float aftT[128][20];
  __shared__ float ndT[32][260];
  const int tid = threadIdx.x;
  const int b = blockIdx.y;
  const int mt = blockIdx.x >> 3;
  const int nt = blockIdx.x & 7;
  const int p0 = mt * 16;
  const int n0 = nt * 256;
  const float spb = log_scale[0] * probs_alpha[0];
  const float isd = 0.088388347648318447f;
  const int tx = tid & 63;
  const int ty = tid >> 6;

  {
    const int pl = tid >> 4;
    const int d0 = (tid & 15) * 8;
    float4 v0 = make_float4(0,0,0,0), v1 = make_float4(0,0,0,0);
    if (p0 + pl < PP){
      const float* src = aft + ((size_t)b * PP + p0 + pl) * DD + d0;
      v0 = *(const float4*)src;
      v1 = *(const float4*)(src + 4);
    }
    aftT[d0+0][pl]=v0.x; aftT[d0+1][pl]=v0.y; aftT[d0+2][pl]=v0.z; aftT[d0+3][pl]=v0.w;
    aftT[d0+4][pl]=v1.x; aftT[d0+5][pl]=v1.y; aftT[d0+6][pl]=v1.z; aftT[d0+7][pl]=v1.w;
  }
  float acc[4][4];
  #pragma unroll
  for (int i = 0; i < 4; i++)
    #pragma unroll
    for (int j = 0; j < 4; j++) acc[i][j] = 0.f;

  for (int c = 0; c < 4; c++){
    __syncthreads();
    {
      const int n = n0 + tid;
      float4 r[8];
      if (n < NN){
        const float* src = nodes + ((size_t)b * NN + n) * DD + c * 32;
        #pragma unroll
        for (int j = 0; j < 8; j++) r[j] = *(const float4*)(src + j*4);
      } else {
        #pragma unroll
        for (int j = 0; j < 8; j++) r[j] = make_float4(0,0,0,0);
      }
      #pragma unroll
      for (int j = 0; j < 8; j++){
        ndT[j*4+0][tid] = r[j].x; ndT[j*4+1][tid] = r[j].y;
        ndT[j*4+2][tid] = r[j].z; ndT[j*4+3][tid] = r[j].w;
      }
    }
    __syncthreads();
    #pragma unroll 8
    for (int kk = 0; kk < 32; kk++){
      const int k = c * 32 + kk;
      const float4 a = *(const float4*)&aftT[k][ty*4];
      const float4 bv = *(const float4*)&ndT[kk][tx*4];
      acc[0][0]+=a.x*bv.x; acc[0][1]+=a.x*bv.y; acc[0][2]+=a.x*bv.z; acc[0][3]+=a.x*bv.w;
      acc[1][0]+=a.y*bv.x; acc[1][1]+=a.y*bv.y; acc[1][2]+=a.y*bv.z; acc[1][3]+=a.y*bv.w;
      acc[2][0]+=a.z*bv.x; acc[2][1]+=a.z*bv.y; acc[2][2]+=a.z*bv.z; acc[2][3]+=a.z*bv.w;
      acc[3][0]+=a.w*bv.x; acc[3][1]+=a.w*bv.y; acc[3][2]+=a.w*bv.z; acc[3][3]+=a.w*bv.w;
    }
  }
  const int n = n0 + tx * 4;
  if (n < NN){
    #pragma unroll
    for (int i = 0; i < 4; i++){
      const int p = p0 + ty * 4 + i;
      if (p < PP){
        const size_t off = ((size_t)b * PP + p) * NN + n;
        const float4 dv = *(const float4*)(dist + off);
        const float4 nv = *(const float4*)(ninf + off);
        float4 s;
        s.x = 10.f * tanhf(acc[i][0]*isd - spb*dv.x) + nv.x;
        s.y = 10.f * tanhf(acc[i][1]*isd - spb*dv.y) + nv.y;
        s.z = 10.f * tanhf(acc[i][2]*isd - spb*dv.z) + nv.z;
        s.w = 10.f * tanhf(acc[i][3]*isd - spb*dv.w) + nv.w;
        *(float4*)(score + off) = s;
      }
    }
  }
}

// ---------------- K4b: row softmax (unchanged)
__global__ __launch_bounds__(256) void k_softmax(
    const float* __restrict__ score, float* __restrict__ out)
{
  __shared__ float s[4][NN];
  __shared__ float red[4][256];
  const int tid = threadIdx.x;
  const int b = blockIdx.y;
  const int p0 = blockIdx.x * 4;
  #pragma unroll
  for (int r = 0; r < 4; r++){
    const float4* src = (const float4*)(score + ((size_t)b * PP + p0 + r) * NN);
    float4* dst = (float4*)&s[r][0];
    for (int i = tid; i < NN/4; i += 256) dst[i] = src[i];
  }
  __syncthreads();
  float mx[4] = {-1e30f,-1e30f,-1e30f,-1e30f};
  for (int n = tid; n < NN; n += 256){
    #pragma unroll
    for (int r = 0; r < 4; r++) mx[r] = fmaxf(mx[r], s[r][n]);
  }
  #pragma unroll
  for (int r = 0; r < 4; r++) red[r][tid] = mx[r];
  __syncthreads();
  for (int st = 128; st > 0; st >>= 1){
    if (tid < st){
      #pragma unroll
      for (int r = 0; r < 4; r++) red[r][tid] = fmaxf(red[r][tid], red[r][tid+st]);
    }
    __syncthreads();
  }
  #pragma unroll
  for (int r = 0; r < 4; r++) mx[r] = red[r][0];
  __syncthreads();
  float ps[4] = {0,0,0,0};
  for (int n = tid; n < NN; n += 256){
    #pragma unroll
    for (int r = 0; r < 4; r++){
      const float e = expf(s[r][n] - mx[r]);
      s[r][n] = e;
      ps[r] += e;
    }
  }
  #pragma unroll
  for (int r = 0; r < 4; r++) red[r][tid] = ps[r];
  __syncthreads();
  for (int st = 128; st > 0; st >>= 1){
    if (tid < st){
      #pragma unroll
      for (int r = 0; r < 4; r++) red[r][tid] += red[r][tid+st];
    }
    __syncthreads();
  }
  float inv[4];
  #pragma unroll
  for (int r = 0; r < 4; r++) inv[r] = 1.f / red[r][0];
  __syncthreads();
  #pragma unroll
  for (int r = 0; r < 4; r++){
    float4* dst = (float4*)(out + ((size_t)b * PP + p0 + r) * NN);
    const float4* srcv = (const float4*)&s[r][0];
    for (int i = tid; i < NN/4; i += 256){
      float4 v = srcv[i];
      v.x *= inv[r]; v.y *= inv[r]; v.z *= inv[r]; v.w *= inv[r];
      dst[i] = v;
    }
  }
}

extern "C" void kernel_launch(void* const* d_in, const int* in_sizes, int n_in,
                              void* d_out, int out_size, void* d_ws, size_t ws_size,
                              hipStream_t stream)
{
  const float* nodes = (const float*)d_in[0];
  const float* last  = (const float*)d_in[1];
  const float* q1    = (const float*)d_in[2];
  const float* q2    = (const float*)d_in[3];
  const float* loadv = (const float*)d_in[4];
  const float* leftv = (const float*)d_in[5];
  const float* dist  = (const float*)d_in[6];
  const float* ninf  = (const float*)d_in[7];
  const float* ls    = (const float*)d_in[8];
  const float* Wq1   = (const float*)d_in[9];
  const float* Wq2   = (const float*)d_in[10];
  const float* Wql   = (const float*)d_in[11];
  const float* Wk    = (const float*)d_in[12];
  const float* Wv    = (const float*)d_in[13];
  const float* aa    = (const float*)d_in[14];
  const float* pa    = (const float*)d_in[15];
  float* out = (float*)d_out;

  char* wsb = (char*)d_ws;
  float*    sq      = (float*)(wsb);                 // 1,638,400 B
  float*    aft     = (float*)(wsb + 1638400);       // 1,638,400 B
  ushort_t* ekkT_hi = (ushort_t*)(wsb + 3276800);    // 16,777,216 B
  ushort_t* ekkT_lo = (ushort_t*)(wsb + 20054016);   // 16,777,216 B
  float*    partial = (float*)(wsb + 36831232);      // 33,554,432 B
  float*    score   = partial;                       // overlap (partial dead)

  k_qproj<<<dim3((BB * PP) / 8), dim3(128), 0, stream>>>(q1, q2, last, loadv, leftv, Wq1, Wq2, Wql, sq);
  k_kv<<<dim3(KPAD / 16, BB), dim3(128), 0, stream>>>(nodes, Wk, Wv, ekkT_hi, ekkT_lo);
  k_aft_mfma<<<dim3(4 * 8, BB), dim3(512), 0, stream>>>(dist, ninf, ekkT_hi, ekkT_lo, ls, aa, partial);
  k_aft_reduce<<<dim3(25, BB), dim3(256), 0, stream>>>(partial, sq, aft);
  k_score_gemm<<<dim3(13 * 8, BB), dim3(256), 0, stream>>>(aft, nodes, dist, ninf, ls, pa, score);
  k_softmax<<<dim3(PP / 4, BB), dim3(256), 0, stream>>>(score, out);
}

// Round 7
// 188.365 us; speedup vs baseline: 2.1017x; 1.1263x over previous
//
#include <hip/hip_runtime.h>
#include <hip/hip_bf16.h>

// CVRPModel: B=16, P=200, N=2000, D=128. Inputs f32, output f32.
// Round 7: k_kv -> MFMA projection emitting ekkT directly (transpose via C/D
// layout), coalesced 256B writes via LDS epilogue. aft via split-bf16 MFMA.
// ws (bytes):
//   sq       @0          1,638,400
//   aft      @1,638,400  1,638,400
//   ekkT_hi  @3,276,800  16,777,216  [b][c:256][k:2048] bf16
//   ekkT_lo  @20,054,016 16,777,216
//   nodes_hi @36,831,232  8,388,608  [b][n:2048][d:128] bf16 (zero-padded n)
//   nodes_lo @45,219,840  8,388,608
//   w_hi     @53,608,448     65,536  [mat:2][c:128][d:128] bf16 (Wk,Wv)
//   w_lo     @53,673,984     65,536
//   partial  @53,739,520 33,554,432  [ks:8][b][p:256][c:256] f32 (score overlaps)
// total 87.3 MB.

#define BB 16
#define PP 200
#define NN 2000
#define DD 128
#define KPAD 2048

typedef __attribute__((ext_vector_type(8))) short short8;
typedef __attribute__((ext_vector_type(4))) float f32x4;
typedef unsigned short ushort_t;

__device__ __forceinline__ ushort_t f2bf(float x){
  union{float f; unsigned int u;} v; v.f = x;
  unsigned int r = v.u + 0x7fffu + ((v.u >> 16) & 1u);
  return (ushort_t)(r >> 16);
}
__device__ __forceinline__ float bf2f(ushort_t h){
  union{unsigned int u; float f;} v; v.u = ((unsigned int)h) << 16; return v.f;
}

// ---------------- K1: q projections + sigmoid (unchanged, passing)
__global__ __launch_bounds__(128) void k_qproj(
    const float* __restrict__ q1, const float* __restrict__ q2,
    const float* __restrict__ last, const float* __restrict__ loadv,
    const float* __restrict__ leftv, const float* __restrict__ Wq1,
    const float* __restrict__ Wq2, const float* __restrict__ Wql,
    float* __restrict__ sq_out)
{
  __shared__ float s1[8][DD], s2[8][DD], s3[8][DD];
  const int d = threadIdx.x;
  const int bp0 = blockIdx.x * 8;
  {
    const float4* g1 = (const float4*)(q1 + (size_t)bp0 * DD);
    const float4* g2 = (const float4*)(q2 + (size_t)bp0 * DD);
    const float4* g3 = (const float4*)(last + (size_t)bp0 * DD);
    float4* t1 = (float4*)&s1[0][0];
    float4* t2 = (float4*)&s2[0][0];
    float4* t3 = (float4*)&s3[0][0];
    #pragma unroll
    for (int k = 0; k < 2; k++){
      const int ii = d + k * 128;
      t1[ii] = g1[ii]; t2[ii] = g2[ii]; t3[ii] = g3[ii];
    }
  }
  __syncthreads();
  float acc[8] = {0,0,0,0,0,0,0,0};
  const float4* w1 = (const float4*)(Wq1 + (size_t)d * DD);
  const float4* w2 = (const float4*)(Wq2 + (size_t)d * DD);
  #pragma unroll 8
  for (int i = 0; i < 32; i++){
    const float4 f = w1[i];
    const int e = i * 4;
    #pragma unroll
    for (int r = 0; r < 8; r++)
      acc[r] += s1[r][e]*f.x + s1[r][e+1]*f.y + s1[r][e+2]*f.z + s1[r][e+3]*f.w;
  }
  #pragma unroll 8
  for (int i = 0; i < 32; i++){
    const float4 f = w2[i];
    const int e = i * 4;
    #pragma unroll
    for (int r = 0; r < 8; r++)
      acc[r] += s2[r][e]*f.x + s2[r][e+1]*f.y + s2[r][e+2]*f.z + s2[r][e+3]*f.w;
  }
  const float* wl = Wql + (size_t)d * (DD + 2);
  for (int e = 0; e < DD; e++){
    const float w = wl[e];
    #pragma unroll
    for (int r = 0; r < 8; r++) acc[r] += s3[r][e] * w;
  }
  const float wld = wl[DD], wlf = wl[DD+1];
  #pragma unroll
  for (int r = 0; r < 8; r++){
    const int bp = bp0 + r;
    const float qv = acc[r] + loadv[bp] * wld + leftv[bp] * wlf;
    sq_out[(size_t)bp * DD + d] = 1.f / (1.f + expf(-qv));
  }
}

// ---------------- prep: nodes f32 -> bf16 hi/lo planes, n zero-padded to 2048.
__global__ __launch_bounds__(256) void k_prep_nodes(
    const float* __restrict__ nodes, ushort_t* __restrict__ nh,
    ushort_t* __restrict__ nl)
{
  const int gid = blockIdx.x * 256 + threadIdx.x;
  const int rid = gid >> 4;           // global row (b,n)
  const int d0 = (gid & 15) * 8;
  const int b = rid >> 11, n = rid & 2047;
  float4 v0 = make_float4(0,0,0,0), v1 = make_float4(0,0,0,0);
  if (n < NN){
    const float* src = nodes + ((size_t)b * NN + n) * DD + d0;
    v0 = *(const float4*)src;
    v1 = *(const float4*)(src + 4);
  }
  const float x[8] = {v0.x,v0.y,v0.z,v0.w,v1.x,v1.y,v1.z,v1.w};
  unsigned int h[4], l[4];
  #pragma unroll
  for (int j = 0; j < 4; j++){
    const ushort_t h0 = f2bf(x[2*j]),   h1 = f2bf(x[2*j+1]);
    const ushort_t l0 = f2bf(x[2*j] - bf2f(h0)), l1 = f2bf(x[2*j+1] - bf2f(h1));
    h[j] = (unsigned int)h0 | ((unsigned int)h1 << 16);
    l[j] = (unsigned int)l0 | ((unsigned int)l1 << 16);
  }
  const size_t o = ((size_t)b * KPAD + n) * DD + d0;
  *(uint4*)(nh + o) = make_uint4(h[0],h[1],h[2],h[3]);
  *(uint4*)(nl + o) = make_uint4(l[0],l[1],l[2],l[3]);
}

// ---------------- prep: Wk,Wv -> bf16 hi/lo [mat][c][d]
__global__ __launch_bounds__(256) void k_prep_w(
    const float* __restrict__ Wk, const float* __restrict__ Wv,
    ushort_t* __restrict__ wh, ushort_t* __restrict__ wl)
{
  const int gid = blockIdx.x * 256 + threadIdx.x;
  const int flat = gid * 8;                 // 0..32767
  const float* W = (flat & 16384) ? Wv : Wk;
  const int idx = flat & 16383;
  const float4 v0 = *(const float4*)(W + idx);
  const float4 v1 = *(const float4*)(W + idx + 4);
  const float x[8] = {v0.x,v0.y,v0.z,v0.w,v1.x,v1.y,v1.z,v1.w};
  unsigned int h[4], l[4];
  #pragma unroll
  for (int j = 0; j < 4; j++){
    const ushort_t h0 = f2bf(x[2*j]),   h1 = f2bf(x[2*j+1]);
    const ushort_t l0 = f2bf(x[2*j] - bf2f(h0)), l1 = f2bf(x[2*j+1] - bf2f(h1));
    h[j] = (unsigned int)h0 | ((unsigned int)h1 << 16);
    l[j] = (unsigned int)l0 | ((unsigned int)l1 << 16);
  }
  *(uint4*)(wh + flat) = make_uint4(h[0],h[1],h[2],h[3]);
  *(uint4*)(wl + flat) = make_uint4(l[0],l[1],l[2],l[3]);
}

// ---------------- K2: ekkT[c][n] via MFMA: D[c][n] = sum_d W[c][d]*nodes[n][d].
// A = W (row=c), B = nodesT (col=n) -- both read 8-contiguous-d from global.
// Block 512 thr = 8 waves (4 wc x 2 wn), tile 128c x 128n. grid (16, B).
// Epilogue: ek=exp(k), ekv=ek*v; hi/lo planes; coalesced 256B/row writes via LDS.
__global__ __launch_bounds__(512) void k_kv_mfma(
    const ushort_t* __restrict__ nodes_hi, const ushort_t* __restrict__ nodes_lo,
    const ushort_t* __restrict__ wh, const ushort_t* __restrict__ wlp,
    ushort_t* __restrict__ ekkT_hi, ushort_t* __restrict__ ekkT_lo)
{
  extern __shared__ ushort_t st[];      // [256][136] = 69,632 B
  const int tid = threadIdx.x;
  const int b = blockIdx.y;
  const int n0 = blockIdx.x * 128;
  const int w  = tid >> 6, l = tid & 63;
  const int wc = w >> 1;                // 0..3 -> c offset wc*32
  const int wn = w & 1;                 // 0..1 -> n offset wn*64
  const int lr = l & 15;
  const int d0b = (l >> 4) * 8;

  f32x4 acc_k[2][4], acc_v[2][4];
  #pragma unroll
  for (int i = 0; i < 2; i++)
    #pragma unroll
    for (int j = 0; j < 4; j++){
      acc_k[i][j] = (f32x4){0.f,0.f,0.f,0.f};
      acc_v[i][j] = (f32x4){0.f,0.f,0.f,0.f};
    }

  #pragma unroll
  for (int kd = 0; kd < 4; kd++){
    const int d0 = kd * 32 + d0b;
    short8 akh[2], akl[2], avh[2], avl[2];
    #pragma unroll
    for (int tf = 0; tf < 2; tf++){
      const int c = wc * 32 + tf * 16 + lr;
      const size_t wo = (size_t)c * DD + d0;
      akh[tf] = *(const short8*)(wh  + wo);
      akl[tf] = *(const short8*)(wlp + wo);
      avh[tf] = *(const short8*)(wh  + 16384 + wo);
      avl[tf] = *(const short8*)(wlp + 16384 + wo);
    }
    short8 bh[4], bl[4];
    #pragma unroll
    for (int tn = 0; tn < 4; tn++){
      const int n = n0 + wn * 64 + tn * 16 + lr;
      const size_t no = ((size_t)b * KPAD + n) * DD + d0;
      bh[tn] = *(const short8*)(nodes_hi + no);
      bl[tn] = *(const short8*)(nodes_lo + no);
    }
    #pragma unroll
    for (int tf = 0; tf < 2; tf++)
      #pragma unroll
      for (int tn = 0; tn < 4; tn++){
        acc_k[tf][tn] = __builtin_amdgcn_mfma_f32_16x16x32_bf16(akh[tf], bh[tn], acc_k[tf][tn], 0, 0, 0);
        acc_k[tf][tn] = __builtin_amdgcn_mfma_f32_16x16x32_bf16(akh[tf], bl[tn], acc_k[tf][tn], 0, 0, 0);
        acc_k[tf][tn] = __builtin_amdgcn_mfma_f32_16x16x32_bf16(akl[tf], bh[tn], acc_k[tf][tn], 0, 0, 0);
        acc_v[tf][tn] = __builtin_amdgcn_mfma_f32_16x16x32_bf16(avh[tf], bh[tn], acc_v[tf][tn], 0, 0, 0);
        acc_v[tf][tn] = __builtin_amdgcn_mfma_f32_16x16x32_bf16(avh[tf], bl[tn], acc_v[tf][tn], 0, 0, 0);
        acc_v[tf][tn] = __builtin_amdgcn_mfma_f32_16x16x32_bf16(avl[tf], bh[tn], acc_v[tf][tn], 0, 0, 0);
      }
  }
  // epilogue: ek = exp(k), ekv = ek * v  (in-register, f32)
  #pragma unroll
  for (int tf = 0; tf < 2; tf++)
    #pragma unroll
    for (int tn = 0; tn < 4; tn++)
      #pragma unroll
      for (int r = 0; r < 4; r++){
        const float ek = expf(acc_k[tf][tn][r]);
        acc_k[tf][tn][r] = ek;
        acc_v[tf][tn][r] = ek * acc_v[tf][tn][r];
      }
  // two plane phases (hi, lo): LDS stage [256 rows][128 n], coalesced write.
  #pragma unroll
  for (int plane = 0; plane < 2; plane++){
    __syncthreads();
    #pragma unroll
    for (int tf = 0; tf < 2; tf++)
      #pragma unroll
      for (int tn = 0; tn < 4; tn++)
        #pragma unroll
        for (int r = 0; r < 4; r++){
          const int row = wc * 32 + tf * 16 + (l >> 4) * 4 + r;
          const int col = wn * 64 + tn * 16 + lr;
          const float vv = acc_v[tf][tn][r];   // ekv
          const float vk = acc_k[tf][tn][r];   // ek
          const ushort_t hv = f2bf(vv), hk = f2bf(vk);
          st[row * 136 + col]         = plane ? f2bf(vv - bf2f(hv)) : hv;
          st[(row + 128) * 136 + col] = plane ? f2bf(vk - bf2f(hk)) : hk;
        }
    __syncthreads();
    const int row = tid >> 1, seg = tid & 1;
    const uint4* src = (const uint4*)(st + row * 136 + seg * 64);
    ushort_t* dp = (plane ? ekkT_lo : ekkT_hi)
                 + ((size_t)b * 256 + row) * KPAD + n0 + seg * 64;
    uint4* dst4 = (uint4*)dp;
    #pragma unroll
    for (int j = 0; j < 8; j++) dst4[j] = src[j];
  }
}

// ---------------- K3a: partial[ks][b][p][c] = sum_k ea[p][k]*ekkT[c][k]
// split-bf16 3-pass MFMA. Block 512 thr = 8 waves, tile 64p x 256c. grid (4*8, B).
__global__ __launch_bounds__(512) void k_aft_mfma(
    const float* __restrict__ dist, const float* __restrict__ ninf,
    const ushort_t* __restrict__ ekkT_hi, const ushort_t* __restrict__ ekkT_lo,
    const float* __restrict__ log_scale, const float* __restrict__ aft_alpha,
    float* __restrict__ partial)
{
  __shared__ __align__(16) ushort_t ea_hi[64][40];
  __shared__ __align__(16) ushort_t ea_lo[64][40];
  const int tid = threadIdx.x;
  const int b = blockIdx.y;
  const int mi = blockIdx.x >> 3;
  const int ks = blockIdx.x & 7;
  const int p0 = mi * 64;
  const int k0 = ks * 256;
  const float scale = log_scale[0] * aft_alpha[0];
  const int w  = tid >> 6;
  const int l  = tid & 63;
  const int wp = w >> 2;
  const int wc = w & 3;
  const int lr = l & 15;
  const int lk = (l >> 4) * 8;

  f32x4 acc[2][4];
  #pragma unroll
  for (int i = 0; i < 2; i++)
    #pragma unroll
    for (int j = 0; j < 4; j++) acc[i][j] = (f32x4){0.f, 0.f, 0.f, 0.f};

  const ushort_t* bptr_h[4];
  const ushort_t* bptr_l[4];
  #pragma unroll
  for (int tc = 0; tc < 4; tc++){
    const int c = wc * 64 + tc * 16 + lr;
    const size_t off = ((size_t)b * 256 + c) * KPAD + k0 + lk;
    bptr_h[tc] = ekkT_hi + off;
    bptr_l[tc] = ekkT_lo + off;
  }

  for (int kc = 0; kc < 8; kc++){
    short8 bh[4], bl[4];
    #pragma unroll
    for (int tc = 0; tc < 4; tc++){
      bh[tc] = *(const short8*)bptr_h[tc];
      bl[tc] = *(const short8*)bptr_l[tc];
      bptr_h[tc] += 32; bptr_l[tc] += 32;
    }
    int idx = tid;
    #pragma unroll
    for (int i = 0; i < 4; i++){
      const int pl = idx >> 5, kk = idx & 31;
      const int p = p0 + pl, kg = k0 + kc * 32 + kk;
      float e = 0.f;
      if (p < PP && kg < NN){
        const size_t o = ((size_t)b * PP + p) * NN + kg;
        e = expf(ninf[o] - scale * dist[o]);
      }
      const ushort_t h = f2bf(e);
      ea_hi[pl][kk] = h;
      ea_lo[pl][kk] = f2bf(e - bf2f(h));
      idx += 512;
    }
    __syncthreads();
    short8 ah[2], al[2];
    #pragma unroll
    for (int tp = 0; tp < 2; tp++){
      const int row = wp * 32 + tp * 16 + lr;
      ah[tp] = *(const short8*)&ea_hi[row][lk];
      al[tp] = *(const short8*)&ea_lo[row][lk];
    }
    #pragma unroll
    for (int tp = 0; tp < 2; tp++)
      #pragma unroll
      for (int tc = 0; tc < 4; tc++){
        acc[tp][tc] = __builtin_amdgcn_mfma_f32_16x16x32_bf16(ah[tp], bh[tc], acc[tp][tc], 0, 0, 0);
        acc[tp][tc] = __builtin_amdgcn_mfma_f32_16x16x32_bf16(ah[tp], bl[tc], acc[tp][tc], 0, 0, 0);
        acc[tp][tc] = __builtin_amdgcn_mfma_f32_16x16x32_bf16(al[tp], bh[tc], acc[tp][tc], 0, 0, 0);
      }
    __syncthreads();
  }
  #pragma unroll
  for (int tp = 0; tp < 2; tp++){
    const int prow = p0 + wp * 32 + tp * 16 + (l >> 4) * 4;
    #pragma unroll
    for (int tc = 0; tc < 4; tc++){
      const int c = wc * 64 + tc * 16 + (l & 15);
      #pragma unroll
      for (int r = 0; r < 4; r++){
        partial[(size_t)ks * 1048576 + ((size_t)b * 256 + prow + r) * 256 + c] = acc[tp][tc][r];
      }
    }
  }
}

// ---------------- K3b: reduce 8 partials; aft = sq * bias/(den+eps). grid (25,B) x 256.
__global__ __launch_bounds__(256) void k_aft_reduce(
    const float* __restrict__ partial, const float* __restrict__ sq,
    float* __restrict__ aft)
{
  const int pl = threadIdx.x >> 7;
  const int c  = threadIdx.x & 127;
  const int b = blockIdx.y;
  #pragma unroll
  for (int i = 0; i < 4; i++){
    const int p = blockIdx.x * 8 + i * 2 + pl;
    const size_t base = ((size_t)b * 256 + p) * 256;
    float bias = 0.f, den = 0.f;
    #pragma unroll
    for (int ksi = 0; ksi < 8; ksi++){
      const float* ptr = partial + (size_t)ksi * 1048576 + base;
      bias += ptr[c];
      den  += ptr[c + 128];
    }
    const size_t o = ((size_t)b * PP + p) * DD + c;
    aft[o] = sq[o] * (bias / (den + 1e-20f));
  }
}

// ---------------- K4a: score GEMM + tanh epilogue (unchanged)
__global__ __launch_bounds__(256) void k_score_gemm(
    const float* __restrict__ aft, const float* __restrict__ nodes,
    const float* __restrict__ dist, const float* __restrict__ ninf,
    const float* __restrict__ log_scale, const float* __restrict__ probs_alpha,
    float* __restrict__ score)
{
  __shared__ float aftT[128][20];
  __shared__ float ndT[32][260];
  const int tid = threadIdx.x;
  const int b = blockIdx.y;
  const int mt = blockIdx.x >> 3;
  const int nt = blockIdx.x & 7;
  const int p0 = mt * 16;
  const int n0 = nt * 256;
  const float spb = log_scale[0] * probs_alpha[0];
  const float isd = 0.088388347648318447f;
  const int tx = tid & 63;
  const int ty = tid >> 6;

  {
    const int pl = tid >> 4;
    const int d0 = (tid & 15) * 8;
    float4 v0 = make_float4(0,0,0,0), v1 = make_float4(0,0,0,0);
    if (p0 + pl < PP){
      const float* src = aft + ((size_t)b * PP + p0 + pl) * DD + d0;
      v0 = *(const float4*)src;
      v1 = *(const float4*)(src + 4);
    }
    aftT[d0+0][pl]=v0.x; aftT[d0+1][pl]=v0.y; aftT[d0+2][pl]=v0.z; aftT[d0+3][pl]=v0.w;
    aftT[d0+4][pl]=v1.x; aftT[d0+5][pl]=v1.y; aftT[d0+6][pl]=v1.z; aftT[d0+7][pl]=v1.w;
  }
  float acc[4][4];
  #pragma unroll
  for (int i = 0; i < 4; i++)
    #pragma unroll
    for (int j = 0; j < 4; j++) acc[i][j] = 0.f;

  for (int c = 0; c < 4; c++){
    __syncthreads();
    {
      const int n = n0 + tid;
      float4 r[8];
      if (n < NN){
        const float* src = nodes + ((size_t)b * NN + n) * DD + c * 32;
        #pragma unroll
        for (int j = 0; j < 8; j++) r[j] = *(const float4*)(src + j*4);
      } else {
        #pragma unroll
        for (int j = 0; j < 8; j++) r[j] = make_float4(0,0,0,0);
      }
      #pragma unroll
      for (int j = 0; j < 8; j++){
        ndT[j*4+0][tid] = r[j].x; ndT[j*4+1][tid] = r[j].y;
        ndT[j*4+2][tid] = r[j].z; ndT[j*4+3][tid] = r[j].w;
      }
    }
    __syncthreads();
    #pragma unroll 8
    for (int kk = 0; kk < 32; kk++){
      const int k = c * 32 + kk;
      const float4 a = *(const float4*)&aftT[k][ty*4];
      const float4 bv = *(const float4*)&ndT[kk][tx*4];
      acc[0][0]+=a.x*bv.x; acc[0][1]+=a.x*bv.y; acc[0][2]+=a.x*bv.z; acc[0][3]+=a.x*bv.w;
      acc[1][0]+=a.y*bv.x; acc[1][1]+=a.y*bv.y; acc[1][2]+=a.y*bv.z; acc[1][3]+=a.y*bv.w;
      acc[2][0]+=a.z*bv.x; acc[2][1]+=a.z*bv.y; acc[2][2]+=a.z*bv.z; acc[2][3]+=a.z*bv.w;
      acc[3][0]+=a.w*bv.x; acc[3][1]+=a.w*bv.y; acc[3][2]+=a.w*bv.z; acc[3][3]+=a.w*bv.w;
    }
  }
  const int n = n0 + tx * 4;
  if (n < NN){
    #pragma unroll
    for (int i = 0; i < 4; i++){
      const int p = p0 + ty * 4 + i;
      if (p < PP){
        const size_t off = ((size_t)b * PP + p) * NN + n;
        const float4 dv = *(const float4*)(dist + off);
        const float4 nv = *(const float4*)(ninf + off);
        float4 s;
        s.x = 10.f * tanhf(acc[i][0]*isd - spb*dv.x) + nv.x;
        s.y = 10.f * tanhf(acc[i][1]*isd - spb*dv.y) + nv.y;
        s.z = 10.f * tanhf(acc[i][2]*isd - spb*dv.z) + nv.z;
        s.w = 10.f * tanhf(acc[i][3]*isd - spb*dv.w) + nv.w;
        *(float4*)(score + off) = s;
      }
    }
  }
}

// ---------------- K4b: row softmax (unchanged)
__global__ __launch_bounds__(256) void k_softmax(
    const float* __restrict__ score, float* __restrict__ out)
{
  __shared__ float s[4][NN];
  __shared__ float red[4][256];
  const int tid = threadIdx.x;
  const int b = blockIdx.y;
  const int p0 = blockIdx.x * 4;
  #pragma unroll
  for (int r = 0; r < 4; r++){
    const float4* src = (const float4*)(score + ((size_t)b * PP + p0 + r) * NN);
    float4* dst = (float4*)&s[r][0];
    for (int i = tid; i < NN/4; i += 256) dst[i] = src[i];
  }
  __syncthreads();
  float mx[4] = {-1e30f,-1e30f,-1e30f,-1e30f};
  for (int n = tid; n < NN; n += 256){
    #pragma unroll
    for (int r = 0; r < 4; r++) mx[r] = fmaxf(mx[r], s[r][n]);
  }
  #pragma unroll
  for (int r = 0; r < 4; r++) red[r][tid] = mx[r];
  __syncthreads();
  for (int st = 128; st > 0; st >>= 1){
    if (tid < st){
      #pragma unroll
      for (int r = 0; r < 4; r++) red[r][tid] = fmaxf(red[r][tid], red[r][tid+st]);
    }
    __syncthreads();
  }
  #pragma unroll
  for (int r = 0; r < 4; r++) mx[r] = red[r][0];
  __syncthreads();
  float ps[4] = {0,0,0,0};
  for (int n = tid; n < NN; n += 256){
    #pragma unroll
    for (int r = 0; r < 4; r++){
      const float e = expf(s[r][n] - mx[r]);
      s[r][n] = e;
      ps[r] += e;
    }
  }
  #pragma unroll
  for (int r = 0; r < 4; r++) red[r][tid] = ps[r];
  __syncthreads();
  for (int st = 128; st > 0; st >>= 1){
    if (tid < st){
      #pragma unroll
      for (int r = 0; r < 4; r++) red[r][tid] += red[r][tid+st];
    }
    __syncthreads();
  }
  float inv[4];
  #pragma unroll
  for (int r = 0; r < 4; r++) inv[r] = 1.f / red[r][0];
  __syncthreads();
  #pragma unroll
  for (int r = 0; r < 4; r++){
    float4* dst = (float4*)(out + ((size_t)b * PP + p0 + r) * NN);
    const float4* srcv = (const float4*)&s[r][0];
    for (int i = tid; i < NN/4; i += 256){
      float4 v = srcv[i];
      v.x *= inv[r]; v.y *= inv[r]; v.z *= inv[r]; v.w *= inv[r];
      dst[i] = v;
    }
  }
}

extern "C" void kernel_launch(void* const* d_in, const int* in_sizes, int n_in,
                              void* d_out, int out_size, void* d_ws, size_t ws_size,
                              hipStream_t stream)
{
  const float* nodes = (const float*)d_in[0];
  const float* last  = (const float*)d_in[1];
  const float* q1    = (const float*)d_in[2];
  const float* q2    = (const float*)d_in[3];
  const float* loadv = (const float*)d_in[4];
  const float* leftv = (const float*)d_in[5];
  const float* dist  = (const float*)d_in[6];
  const float* ninf  = (const float*)d_in[7];
  const float* ls    = (const float*)d_in[8];
  const float* Wq1   = (const float*)d_in[9];
  const float* Wq2   = (const float*)d_in[10];
  const float* Wql   = (const float*)d_in[11];
  const float* Wk    = (const float*)d_in[12];
  const float* Wv    = (const float*)d_in[13];
  const float* aa    = (const float*)d_in[14];
  const float* pa    = (const float*)d_in[15];
  float* out = (float*)d_out;

  char* wsb = (char*)d_ws;
  float*    sq       = (float*)(wsb);                 // 1,638,400 B
  float*    aft      = (float*)(wsb + 1638400);       // 1,638,400 B
  ushort_t* ekkT_hi  = (ushort_t*)(wsb + 3276800);    // 16,777,216 B
  ushort_t* ekkT_lo  = (ushort_t*)(wsb + 20054016);   // 16,777,216 B
  ushort_t* nodes_hi = (ushort_t*)(wsb + 36831232);   //  8,388,608 B
  ushort_t* nodes_lo = (ushort_t*)(wsb + 45219840);   //  8,388,608 B
  ushort_t* w_hi     = (ushort_t*)(wsb + 53608448);   //     65,536 B
  ushort_t* w_lo     = (ushort_t*)(wsb + 53673984);   //     65,536 B
  float*    partial  = (float*)(wsb + 53739520);      // 33,554,432 B
  float*    score    = partial;                       // overlap (partial dead)

  k_qproj<<<dim3((BB * PP) / 8), dim3(128), 0, stream>>>(q1, q2, last, loadv, leftv, Wq1, Wq2, Wql, sq);
  k_prep_nodes<<<dim3(2048), dim3(256), 0, stream>>>(nodes, nodes_hi, nodes_lo);
  k_prep_w<<<dim3(16), dim3(256), 0, stream>>>(Wk, Wv, w_hi, w_lo);
  k_kv_mfma<<<dim3(16, BB), dim3(512), 69632, stream>>>(nodes_hi, nodes_lo, w_hi, w_lo, ekkT_hi, ekkT_lo);
  k_aft_mfma<<<dim3(4 * 8, BB), dim3(512), 0, stream>>>(dist, ninf, ekkT_hi, ekkT_lo, ls, aa, partial);
  k_aft_reduce<<<dim3(25, BB), dim3(256), 0, stream>>>(partial, sq, aft);
  k_score_gemm<<<dim3(13 * 8, BB), dim3(256), 0, stream>>>(aft, nodes, dist, ninf, ls, pa, score);
  k_softmax<<<dim3(PP / 4, BB), dim3(256), 0, stream>>>(score, out);
}